// Round 3
// baseline (2542.567 us; speedup 1.0000x reference)
//
#include <hip/hip_runtime.h>
#include <hip/hip_bf16.h>

#define NU 50000
#define NE 100000
#define DIM 64
#define NRELS 16
#define EKG 1500000
#define EIN 1000000

// ---- ordered-uint encoding for float atomicMax ----
__device__ __forceinline__ unsigned ford(float f) {
    unsigned u = __float_as_uint(f);
    return (u & 0x80000000u) ? ~u : (u | 0x80000000u);
}
__device__ __forceinline__ float fdec(unsigned u) {
    unsigned b = (u & 0x80000000u) ? (u ^ 0x80000000u) : ~u;
    return __uint_as_float(b);
}

// qm[i][c] = sum_k ent[i][k] * WQ[k][c]   (4 rows per 256-thread block)
__global__ __launch_bounds__(256) void k_gemm(const float* __restrict__ ent,
                                              const float* __restrict__ wq,
                                              float* __restrict__ qm, int nrows) {
    __shared__ float sW[64 * 64];
    __shared__ float sR[4][64];
    int t = threadIdx.x;
    for (int i = t; i < 4096; i += 256) sW[i] = wq[i];
    int r = t >> 6, c = t & 63;
    int row = blockIdx.x * 4 + r;
    sR[r][c] = (row < nrows) ? ent[row * 64 + c] : 0.f;
    __syncthreads();
    float acc = 0.f;
#pragma unroll
    for (int k = 0; k < 64; k++) acc += sR[r][k] * sW[k * 64 + c];
    if (row < nrows) qm[row * 64 + c] = acc;
}

// per-edge attention scores (2 heads) + segment max via ordered atomicMax
__global__ __launch_bounds__(256) void k_score(const float* __restrict__ qm,
                                               const float* __restrict__ relf,
                                               const int* __restrict__ eh,
                                               const int* __restrict__ et,
                                               const int* __restrict__ ety,
                                               float* __restrict__ score,
                                               unsigned* __restrict__ segmax) {
    int e = blockIdx.x * blockDim.x + threadIdx.x;
    if (e >= EKG) return;
    int h = eh[e], tl = et[e], rr = ety[e] - 1;
    const float4* qh = (const float4*)(qm + (long)h * 64);
    const float4* qt = (const float4*)(qm + (long)tl * 64);
    const float4* rl = (const float4*)(relf + rr * 64);
    float s0 = 0.f, s1 = 0.f;
#pragma unroll
    for (int j = 0; j < 8; j++) {
        float4 a = qh[j], b = qt[j], c = rl[j];
        s0 += a.x * b.x * c.x + a.y * b.y * c.y + a.z * b.z * c.z + a.w * b.w * c.w;
    }
#pragma unroll
    for (int j = 8; j < 16; j++) {
        float4 a = qh[j], b = qt[j], c = rl[j];
        s1 += a.x * b.x * c.x + a.y * b.y * c.y + a.z * b.z * c.z + a.w * b.w * c.w;
    }
    const float sc = 0.17677669529663687f; // 1/sqrt(32)
    s0 *= sc; s1 *= sc;
    score[e * 2 + 0] = s0;
    score[e * 2 + 1] = s1;
    atomicMax(&segmax[h * 2 + 0], ford(s0));
    atomicMax(&segmax[h * 2 + 1], ford(s1));
}

// ex = exp(score - segmax); segment sum
__global__ void k_exp(const int* __restrict__ eh, float* __restrict__ score,
                      const unsigned* __restrict__ segmax, float* __restrict__ segsum) {
    int i = blockIdx.x * blockDim.x + threadIdx.x;
    if (i >= EKG * 2) return;
    int e = i >> 1, h = i & 1;
    int hd = eh[e];
    float m = fdec(segmax[hd * 2 + h]);
    float ex = __expf(score[i] - m);
    score[i] = ex;
    atomicAdd(&segsum[hd * 2 + h], ex);
}

// message aggregation: one thread per (edge, dim)
__global__ void k_msg(const int* __restrict__ eh, const int* __restrict__ et,
                      const int* __restrict__ ety, const float* __restrict__ ex,
                      const float* __restrict__ segsum, const float* __restrict__ entCur,
                      const float* __restrict__ relf, float* __restrict__ entNext) {
    int i = blockIdx.x * blockDim.x + threadIdx.x; // EKG*64 = 96M < 2^31
    int e = i >> 6, d = i & 63, h = d >> 5;
    if (e >= EKG) return;
    int hd = eh[e], tl = et[e], rr = ety[e] - 1;
    float attn = ex[e * 2 + h] / segsum[hd * 2 + h];
    float val = entCur[(long)tl * 64 + d] * relf[rr * 64 + d] * attn;
    atomicAdd(&entNext[(long)hd * 64 + d], val);
}

// L2 row normalize (one wave per row, 4 rows per block)
__global__ __launch_bounds__(256) void k_norm(float* __restrict__ a, int nrows) {
    int row = blockIdx.x * 4 + (threadIdx.x >> 6);
    int c = threadIdx.x & 63;
    if (row >= nrows) return;
    float v = a[(long)row * 64 + c];
    float s = v * v;
    for (int off = 32; off; off >>= 1) s += __shfl_down(s, off, 64);
    s = __shfl(s, 0, 64);
    float scale = 1.f / fmaxf(sqrtf(s), 1e-12f);
    a[(long)row * 64 + c] = v * scale;
}

// bipartite aggregation: user <- item and entity <- user
__global__ void k_inter(const int* __restrict__ iu, const int* __restrict__ ii,
                        const float* __restrict__ w, const float* __restrict__ entCur,
                        const float* __restrict__ usrCur, float* __restrict__ usrNext,
                        float* __restrict__ entNext) {
    int i = blockIdx.x * blockDim.x + threadIdx.x; // EIN*64 = 64M
    int e = i >> 6, d = i & 63;
    if (e >= EIN) return;
    int u = iu[e], it = ii[e];
    float wf = w[e];
    atomicAdd(&usrNext[(long)u * 64 + d], wf * entCur[(long)it * 64 + d]);
    atomicAdd(&entNext[(long)it * 64 + d], wf * usrCur[(long)u * 64 + d]);
}

// out = concat(mean(usr0..2), mean(ent0..2)) as f32
__global__ void k_final(const float* __restrict__ u0, const float* __restrict__ u1,
                        const float* __restrict__ u2, const float* __restrict__ e0,
                        const float* __restrict__ e1, const float* __restrict__ e2,
                        float* __restrict__ out) {
    int i = blockIdx.x * blockDim.x + threadIdx.x;
    const float inv3 = 1.f / 3.f;
    if (i < NU * DIM) {
        out[i] = (u0[i] + u1[i] + u2[i]) * inv3;
    } else if (i < (NU + NE) * DIM) {
        int j = i - NU * DIM;
        out[i] = (e0[j] + e1[j] + e2[j]) * inv3;
    }
}

extern "C" void kernel_launch(void* const* d_in, const int* in_sizes, int n_in,
                              void* d_out, int out_size, void* d_ws, size_t ws_size,
                              hipStream_t stream) {
    const float* usr0  = (const float*)d_in[1];   // [NU, 64]
    const float* ent0  = (const float*)d_in[2];   // [NE, 64]
    const int*   inter = (const int*)d_in[3];     // [2, EIN]
    const float* iwf   = (const float*)d_in[4];   // [EIN]
    const int*   eidx  = (const int*)d_in[5];     // [2, EKG]
    const int*   etype = (const int*)d_in[6];     // [EKG]
    const float* relf  = (const float*)d_in[7];   // [16, 64]
    const float* wqf   = (const float*)d_in[8];   // [64, 64]
    float* out = (float*)d_out;

    const int* eh = eidx;
    const int* et = eidx + EKG;
    const int* iu = inter;
    const int* ii = inter + EIN;

    // ---- workspace layout (f32), ~114.4 MB (ws proven >= 158 MB in R2) ----
    float* p = (float*)d_ws;
    float* qm   = p;         p += (long)NE * DIM;   // 6.4M
    float* ent1 = p;         p += (long)NE * DIM;
    float* ent2 = p;         p += (long)NE * DIM;
    float* usr1 = p;         p += (long)NU * DIM;   // 3.2M
    float* usr2 = p;         p += (long)NU * DIM;
    float* ex   = p;         p += (long)EKG * 2;    // 3M
    unsigned* segmax = (unsigned*)p; p += (long)NE * 2;
    float* segsum = p;       p += (long)NE * 2;

    const int B = 256;
    const float* entBuf[3] = {ent0, ent1, ent2};
    const float* usrBuf[3] = {usr0, usr1, usr2};

    for (int L = 0; L < 2; L++) {
        const float* entCur = entBuf[L];
        const float* usrCur = usrBuf[L];
        float* entNxt = (float*)entBuf[L + 1];
        float* usrNxt = (float*)usrBuf[L + 1];

        hipMemsetAsync(entNxt, 0, (size_t)NE * DIM * 4, stream);
        hipMemsetAsync(usrNxt, 0, (size_t)NU * DIM * 4, stream);
        hipMemsetAsync(segmax, 0, (size_t)NE * 2 * 4, stream);
        hipMemsetAsync(segsum, 0, (size_t)NE * 2 * 4, stream);

        k_gemm<<<NE / 4, 256, 0, stream>>>(entCur, wqf, qm, NE);
        k_score<<<(EKG + B - 1) / B, B, 0, stream>>>(qm, relf, eh, et, etype, ex, segmax);
        k_exp<<<(EKG * 2 + B - 1) / B, B, 0, stream>>>(eh, ex, segmax, segsum);
        k_msg<<<(EKG * 64) / B, B, 0, stream>>>(eh, et, etype, ex, segsum, entCur, relf, entNxt);
        k_norm<<<NE / 4, 256, 0, stream>>>(entNxt, NE);
        k_inter<<<(EIN * 64) / B, B, 0, stream>>>(iu, ii, iwf, entCur, usrCur, usrNxt, entNxt);
    }

    k_final<<<((NU + NE) * DIM + B - 1) / B, B, 0, stream>>>(usr0, usr1, usr2,
                                                             ent0, ent1, ent2, out);
}

// Round 4
// 2164.098 us; speedup vs baseline: 1.1749x; 1.1749x over previous
//
#include <hip/hip_runtime.h>

#define NU 50000
#define NE 100000
#define DIM 64
#define NRELS 16
#define EKG 1500000
#define EIN 1000000
#define CAP 64   // per-node LDS score cap; deg>CAP handled by recompute fallback

// qm[i][c] = sum_k ent[i][k] * WQ[k][c]   (4 rows per 256-thread block)
__global__ __launch_bounds__(256) void k_gemm(const float* __restrict__ ent,
                                              const float* __restrict__ wq,
                                              float* __restrict__ qm, int nrows) {
    __shared__ float sW[64 * 64];
    __shared__ float sR[4][64];
    int t = threadIdx.x;
    for (int i = t; i < 4096; i += 256) sW[i] = wq[i];
    int r = t >> 6, c = t & 63;
    int row = blockIdx.x * 4 + r;
    sR[r][c] = (row < nrows) ? ent[row * 64 + c] : 0.f;
    __syncthreads();
    float acc = 0.f;
#pragma unroll
    for (int k = 0; k < 64; k++) acc += sR[r][k] * sW[k * 64 + c];
    if (row < nrows) qm[row * 64 + c] = acc;
}

// histogram for the three CSRs
__global__ void k_hist(const int* __restrict__ eh, const int* __restrict__ iu,
                       const int* __restrict__ ii, int* kg_cnt, int* ui_cnt, int* iu_cnt) {
    int e = blockIdx.x * blockDim.x + threadIdx.x;
    if (e < EKG) atomicAdd(&kg_cnt[eh[e]], 1);
    if (e < EIN) { atomicAdd(&ui_cnt[iu[e]], 1); atomicAdd(&iu_cnt[ii[e]], 1); }
}

// single-block exclusive scan: off[0..n], cur[0..n-1] = copy of off
__global__ __launch_bounds__(1024) void k_scan(const int* __restrict__ cnt,
                                               int* __restrict__ off,
                                               int* __restrict__ cur, int n) {
    __shared__ int part[1024];
    __shared__ int base[1024];
    int t = threadIdx.x;
    int chunk = (n + 1023) >> 10;
    int lo = t * chunk; if (lo > n) lo = n;
    int hi = lo + chunk; if (hi > n) hi = n;
    int s = 0;
    for (int i = lo; i < hi; i++) s += cnt[i];
    part[t] = s;
    __syncthreads();
    if (t == 0) { int run = 0; for (int i = 0; i < 1024; i++) { base[i] = run; run += part[i]; } }
    __syncthreads();
    int run = base[t];
    for (int i = lo; i < hi; i++) { off[i] = run; cur[i] = run; run += cnt[i]; }
    if (t == 1023) off[n] = run;
}

// scatter edges into CSR slots
__global__ void k_scatter(const int* __restrict__ eh, const int* __restrict__ et,
                          const int* __restrict__ ety, const int* __restrict__ iu,
                          const int* __restrict__ ii, const float* __restrict__ iw,
                          int* kg_cur, unsigned* __restrict__ kg_tr,
                          int* ui_cur, int* __restrict__ ui_item, float* __restrict__ ui_w,
                          int* iu_cur, int* __restrict__ iu_user, float* __restrict__ iu_wv) {
    int e = blockIdx.x * blockDim.x + threadIdx.x;
    if (e < EKG) {
        int pos = atomicAdd(&kg_cur[eh[e]], 1);
        kg_tr[pos] = (unsigned)et[e] | ((unsigned)(ety[e] - 1) << 17);
    }
    if (e < EIN) {
        int u = iu[e], it = ii[e]; float w = iw[e];
        int p1 = atomicAdd(&ui_cur[u], 1); ui_item[p1] = it; ui_w[p1] = w;
        int p2 = atomicAdd(&iu_cur[it], 1); iu_user[p2] = u; iu_wv[p2] = w;
    }
}

// fused per-node entity aggregation: scores + softmax + weighted gather +
// L2 normalize + user->entity gather. One wave per node, lane = dim.
__global__ __launch_bounds__(256) void k_ent(const float* __restrict__ qm,
        const float* __restrict__ relf, const float* __restrict__ entCur,
        const float* __restrict__ usrCur,
        const int* __restrict__ kg_off, const unsigned* __restrict__ kg_tr,
        const int* __restrict__ iu_off, const int* __restrict__ iu_user,
        const float* __restrict__ iu_w, float* __restrict__ entNxt) {
    __shared__ float sLds[4][CAP][2];
    int w = threadIdx.x >> 6;
    int node = blockIdx.x * 4 + w;
    if (node >= NE) return;
    int d = threadIdx.x & 63;
    int half = d >> 5;
    const float SC = 0.17677669529663687f; // 1/sqrt(32)
    float qh = qm[(long)node * 64 + d];
    int b0 = kg_off[node], b1 = kg_off[node + 1];
    int deg = b1 - b0;

    // pass A: compute per-edge per-head scores, keep in LDS, track max
    float m = -INFINITY;
    for (int s = b0; s < b1; s++) {
        unsigned tr = kg_tr[s];
        int tl = tr & 0x1FFFF, rr = tr >> 17;
        float p = qh * qm[(long)tl * 64 + d] * relf[rr * 64 + d];
        p += __shfl_xor(p, 16, 64);
        p += __shfl_xor(p, 8, 64);
        p += __shfl_xor(p, 4, 64);
        p += __shfl_xor(p, 2, 64);
        p += __shfl_xor(p, 1, 64);
        float sc = p * SC;
        int i = s - b0;
        if (i < CAP && (d & 31) == 0) sLds[w][i][half] = sc;
        m = fmaxf(m, sc);
    }
    // pass B: exp-sum
    float ssum = 0.f;
    for (int s = b0; s < b1; s++) {
        int i = s - b0;
        float sc;
        if (i < CAP) sc = sLds[w][i][half];
        else { // fallback recompute (practically never taken)
            unsigned tr = kg_tr[s];
            int tl = tr & 0x1FFFF, rr = tr >> 17;
            float p = qh * qm[(long)tl * 64 + d] * relf[rr * 64 + d];
            p += __shfl_xor(p, 16, 64); p += __shfl_xor(p, 8, 64);
            p += __shfl_xor(p, 4, 64);  p += __shfl_xor(p, 2, 64);
            p += __shfl_xor(p, 1, 64);
            sc = p * SC;
        }
        ssum += __expf(sc - m);
    }
    float inv = (deg > 0) ? 1.f / ssum : 0.f;
    // pass C: attention-weighted value gather
    float acc = 0.f;
    for (int s = b0; s < b1; s++) {
        unsigned tr = kg_tr[s];
        int tl = tr & 0x1FFFF, rr = tr >> 17;
        int i = s - b0;
        float sc;
        if (i < CAP) sc = sLds[w][i][half];
        else {
            float p = qh * qm[(long)tl * 64 + d] * relf[rr * 64 + d];
            p += __shfl_xor(p, 16, 64); p += __shfl_xor(p, 8, 64);
            p += __shfl_xor(p, 4, 64);  p += __shfl_xor(p, 2, 64);
            p += __shfl_xor(p, 1, 64);
            sc = p * SC;
        }
        float attn = __expf(sc - m) * inv;
        acc += entCur[(long)tl * 64 + d] * relf[rr * 64 + d] * attn;
    }
    // L2 normalize across the 64-dim row
    float ss = acc * acc;
    for (int o = 32; o; o >>= 1) ss += __shfl_xor(ss, o, 64);
    float scale = 1.f / fmaxf(sqrtf(ss), 1e-12f);
    acc *= scale;
    // + user -> entity contributions
    int c0 = iu_off[node], c1 = iu_off[node + 1];
    for (int s = c0; s < c1; s++)
        acc += iu_w[s] * usrCur[(long)iu_user[s] * 64 + d];
    entNxt[(long)node * 64 + d] = acc;
}

// user <- item gather
__global__ __launch_bounds__(256) void k_usr(const float* __restrict__ entCur,
        const int* __restrict__ ui_off, const int* __restrict__ ui_item,
        const float* __restrict__ ui_w, float* __restrict__ usrNxt) {
    int node = blockIdx.x * 4 + (threadIdx.x >> 6);
    if (node >= NU) return;
    int d = threadIdx.x & 63;
    int b0 = ui_off[node], b1 = ui_off[node + 1];
    float acc = 0.f;
    for (int s = b0; s < b1; s++)
        acc += ui_w[s] * entCur[(long)ui_item[s] * 64 + d];
    usrNxt[(long)node * 64 + d] = acc;
}

// out = concat(mean(usr0..2), mean(ent0..2))
__global__ void k_final(const float* __restrict__ u0, const float* __restrict__ u1,
                        const float* __restrict__ u2, const float* __restrict__ e0,
                        const float* __restrict__ e1, const float* __restrict__ e2,
                        float* __restrict__ out) {
    int i = blockIdx.x * blockDim.x + threadIdx.x;
    const float inv3 = 1.f / 3.f;
    if (i < NU * DIM) {
        out[i] = (u0[i] + u1[i] + u2[i]) * inv3;
    } else if (i < (NU + NE) * DIM) {
        int j = i - NU * DIM;
        out[i] = (e0[j] + e1[j] + e2[j]) * inv3;
    }
}

extern "C" void kernel_launch(void* const* d_in, const int* in_sizes, int n_in,
                              void* d_out, int out_size, void* d_ws, size_t ws_size,
                              hipStream_t stream) {
    const float* usr0  = (const float*)d_in[1];   // [NU, 64]
    const float* ent0  = (const float*)d_in[2];   // [NE, 64]
    const int*   inter = (const int*)d_in[3];     // [2, EIN]
    const float* iwf   = (const float*)d_in[4];   // [EIN]
    const int*   eidx  = (const int*)d_in[5];     // [2, EKG]
    const int*   etype = (const int*)d_in[6];     // [EKG]
    const float* relf  = (const float*)d_in[7];   // [16, 64]
    const float* wqf   = (const float*)d_in[8];   // [64, 64]
    float* out = (float*)d_out;

    const int* eh = eidx;
    const int* et = eidx + EKG;
    const int* iu = inter;
    const int* ii = inter + EIN;

    // ---- workspace layout (4B words), ~127 MB total ----
    float* p = (float*)d_ws;
    float* qm   = p;  p += (long)NE * DIM;
    float* ent1 = p;  p += (long)NE * DIM;
    float* ent2 = p;  p += (long)NE * DIM;
    float* usr1 = p;  p += (long)NU * DIM;
    float* usr2 = p;  p += (long)NU * DIM;
    int* kg_cnt = (int*)p;      p += NE;
    int* kg_off = (int*)p;      p += NE + 1;
    int* kg_cur = (int*)p;      p += NE;
    int* ui_cnt = (int*)p;      p += NU;
    int* ui_off = (int*)p;      p += NU + 1;
    int* ui_cur = (int*)p;      p += NU;
    int* iu_cnt = (int*)p;      p += NE;
    int* iu_off = (int*)p;      p += NE + 1;
    int* iu_cur = (int*)p;      p += NE;
    unsigned* kg_tr = (unsigned*)p; p += EKG;
    int* ui_item = (int*)p;     p += EIN;
    float* ui_w  = p;           p += EIN;
    int* iu_user = (int*)p;     p += EIN;
    float* iu_wv = p;           p += EIN;

    const int B = 256;
    // ---- CSR build (once per call) ----
    hipMemsetAsync(kg_cnt, 0, NE * 4, stream);
    hipMemsetAsync(ui_cnt, 0, NU * 4, stream);
    hipMemsetAsync(iu_cnt, 0, NE * 4, stream);
    int gEdge = (EKG + B - 1) / B;
    k_hist<<<gEdge, B, 0, stream>>>(eh, iu, ii, kg_cnt, ui_cnt, iu_cnt);
    k_scan<<<1, 1024, 0, stream>>>(kg_cnt, kg_off, kg_cur, NE);
    k_scan<<<1, 1024, 0, stream>>>(ui_cnt, ui_off, ui_cur, NU);
    k_scan<<<1, 1024, 0, stream>>>(iu_cnt, iu_off, iu_cur, NE);
    k_scatter<<<gEdge, B, 0, stream>>>(eh, et, etype, iu, ii, iwf,
                                       kg_cur, kg_tr, ui_cur, ui_item, ui_w,
                                       iu_cur, iu_user, iu_wv);

    const float* entBuf[3] = {ent0, ent1, ent2};
    const float* usrBuf[3] = {usr0, usr1, usr2};

    for (int L = 0; L < 2; L++) {
        const float* entCur = entBuf[L];
        const float* usrCur = usrBuf[L];
        float* entNxt = (float*)entBuf[L + 1];
        float* usrNxt = (float*)usrBuf[L + 1];

        k_gemm<<<NE / 4, 256, 0, stream>>>(entCur, wqf, qm, NE);
        k_ent<<<(NE + 3) / 4, 256, 0, stream>>>(qm, relf, entCur, usrCur,
                                                kg_off, kg_tr, iu_off, iu_user,
                                                iu_wv, entNxt);
        k_usr<<<(NU + 3) / 4, 256, 0, stream>>>(entCur, ui_off, ui_item, ui_w, usrNxt);
    }

    k_final<<<((NU + NE) * DIM + B - 1) / B, B, 0, stream>>>(usr0, usr1, usr2,
                                                             ent0, ent1, ent2, out);
}

// Round 5
// 1501.062 us; speedup vs baseline: 1.6938x; 1.4417x over previous
//
#include <hip/hip_runtime.h>

#define NU 50000
#define NE 100000
#define DIM 64
#define NRELS 16
#define EKG 1500000
#define EIN 1000000

// qm[i][c] = sum_k ent[i][k] * WQ[k][c]   (4 rows per 256-thread block)
__global__ __launch_bounds__(256) void k_gemm(const float* __restrict__ ent,
                                              const float* __restrict__ wq,
                                              float* __restrict__ qm, int nrows) {
    __shared__ float sW[64 * 64];
    __shared__ float sR[4][64];
    int t = threadIdx.x;
    for (int i = t; i < 4096; i += 256) sW[i] = wq[i];
    int r = t >> 6, c = t & 63;
    int row = blockIdx.x * 4 + r;
    sR[r][c] = (row < nrows) ? ent[row * 64 + c] : 0.f;
    __syncthreads();
    float acc = 0.f;
#pragma unroll
    for (int k = 0; k < 64; k++) acc += sR[r][k] * sW[k * 64 + c];
    if (row < nrows) qm[row * 64 + c] = acc;
}

// histogram for the three CSRs
__global__ void k_hist(const int* __restrict__ eh, const int* __restrict__ iu,
                       const int* __restrict__ ii, int* kg_cnt, int* ui_cnt, int* iu_cnt) {
    int e = blockIdx.x * blockDim.x + threadIdx.x;
    if (e < EKG) atomicAdd(&kg_cnt[eh[e]], 1);
    if (e < EIN) { atomicAdd(&ui_cnt[iu[e]], 1); atomicAdd(&iu_cnt[ii[e]], 1); }
}

// single-block exclusive scan: off[0..n], cur[0..n-1] = copy of off
__global__ __launch_bounds__(1024) void k_scan(const int* __restrict__ cnt,
                                               int* __restrict__ off,
                                               int* __restrict__ cur, int n) {
    __shared__ int part[1024];
    __shared__ int base[1024];
    int t = threadIdx.x;
    int chunk = (n + 1023) >> 10;
    int lo = t * chunk; if (lo > n) lo = n;
    int hi = lo + chunk; if (hi > n) hi = n;
    int s = 0;
    for (int i = lo; i < hi; i++) s += cnt[i];
    part[t] = s;
    __syncthreads();
    if (t == 0) { int run = 0; for (int i = 0; i < 1024; i++) { base[i] = run; run += part[i]; } }
    __syncthreads();
    int run = base[t];
    for (int i = lo; i < hi; i++) { off[i] = run; cur[i] = run; run += cnt[i]; }
    if (t == 1023) off[n] = run;
}

// scatter edges into CSR slots
__global__ void k_scatter(const int* __restrict__ eh, const int* __restrict__ et,
                          const int* __restrict__ ety, const int* __restrict__ iu,
                          const int* __restrict__ ii, const float* __restrict__ iw,
                          int* kg_cur, unsigned* __restrict__ kg_tr,
                          int* ui_cur, int* __restrict__ ui_item, float* __restrict__ ui_w,
                          int* iu_cur, int* __restrict__ iu_user, float* __restrict__ iu_wv) {
    int e = blockIdx.x * blockDim.x + threadIdx.x;
    if (e < EKG) {
        int pos = atomicAdd(&kg_cur[eh[e]], 1);
        kg_tr[pos] = (unsigned)et[e] | ((unsigned)(ety[e] - 1) << 17);
    }
    if (e < EIN) {
        int u = iu[e], it = ii[e]; float w = iw[e];
        int p1 = atomicAdd(&ui_cur[u], 1); ui_item[p1] = it; ui_w[p1] = w;
        int p2 = atomicAdd(&iu_cur[it], 1); iu_user[p2] = u; iu_wv[p2] = w;
    }
}

#define SHFL_RED(p) \
    p += __shfl_xor(p, 16, 64); p += __shfl_xor(p, 8, 64); \
    p += __shfl_xor(p, 4, 64);  p += __shfl_xor(p, 2, 64); \
    p += __shfl_xor(p, 1, 64);

// fused per-node entity aggregation: single-pass online softmax + weighted
// gather + L2 normalize + user->entity gather. One wave per node, lane = dim.
__global__ __launch_bounds__(256) void k_ent(const float* __restrict__ qm,
        const float* __restrict__ relf, const float* __restrict__ entCur,
        const float* __restrict__ usrCur,
        const int* __restrict__ kg_off, const unsigned* __restrict__ kg_tr,
        const int* __restrict__ iu_off, const int* __restrict__ iu_user,
        const float* __restrict__ iu_w, float* __restrict__ entNxt) {
    int w = __builtin_amdgcn_readfirstlane(threadIdx.x >> 6);
    int node = blockIdx.x * 4 + w;
    if (node >= NE) return;
    int d = threadIdx.x & 63;
    const float SC = 0.17677669529663687f; // 1/sqrt(32)
    float qh = qm[(long)node * 64 + d];
    int b0 = kg_off[node], b1 = kg_off[node + 1];
    int deg = b1 - b0;

    float m = -INFINITY, ssum = 0.f, acc = 0.f;
    int s = b0;
    for (; s + 4 <= b1; s += 4) {
        float sc[4], val[4];
#pragma unroll
        for (int j = 0; j < 4; j++) {
            unsigned tr = kg_tr[s + j];
            int tl = tr & 0x1FFFF, rr = tr >> 17;
            float rl = relf[rr * 64 + d];
            float qt = qm[(long)tl * 64 + d];
            val[j] = entCur[(long)tl * 64 + d] * rl;
            float p = qh * qt * rl;
            SHFL_RED(p)
            sc[j] = p * SC;
        }
        float cmax = fmaxf(fmaxf(sc[0], sc[1]), fmaxf(sc[2], sc[3]));
        float mn = fmaxf(m, cmax);
        float scale = __expf(m - mn); // first chunk: exp(-inf)=0
        ssum *= scale; acc *= scale;
#pragma unroll
        for (int j = 0; j < 4; j++) {
            float e = __expf(sc[j] - mn);
            ssum += e;
            acc += val[j] * e;
        }
        m = mn;
    }
    for (; s < b1; s++) {
        unsigned tr = kg_tr[s];
        int tl = tr & 0x1FFFF, rr = tr >> 17;
        float rl = relf[rr * 64 + d];
        float qt = qm[(long)tl * 64 + d];
        float v = entCur[(long)tl * 64 + d] * rl;
        float p = qh * qt * rl;
        SHFL_RED(p)
        float scv = p * SC;
        float mn = fmaxf(m, scv);
        float scale = __expf(m - mn);
        float e = __expf(scv - mn);
        ssum = ssum * scale + e;
        acc = acc * scale + v * e;
        m = mn;
    }
    if (deg > 0) acc /= ssum;

    // L2 normalize across the 64-dim row
    float ss = acc * acc;
    SHFL_RED(ss)
    ss += __shfl_xor(ss, 32, 64);
    float scale = 1.f / fmaxf(sqrtf(ss), 1e-12f);
    acc *= scale;

    // + user -> entity contributions (x4 unrolled gather)
    int c0 = iu_off[node], c1 = iu_off[node + 1];
    int t = c0;
    for (; t + 4 <= c1; t += 4) {
        float a0 = iu_w[t + 0] * usrCur[(long)iu_user[t + 0] * 64 + d];
        float a1 = iu_w[t + 1] * usrCur[(long)iu_user[t + 1] * 64 + d];
        float a2 = iu_w[t + 2] * usrCur[(long)iu_user[t + 2] * 64 + d];
        float a3 = iu_w[t + 3] * usrCur[(long)iu_user[t + 3] * 64 + d];
        acc += (a0 + a1) + (a2 + a3);
    }
    for (; t < c1; t++)
        acc += iu_w[t] * usrCur[(long)iu_user[t] * 64 + d];
    entNxt[(long)node * 64 + d] = acc;
}

// user <- item gather (x4 unrolled)
__global__ __launch_bounds__(256) void k_usr(const float* __restrict__ entCur,
        const int* __restrict__ ui_off, const int* __restrict__ ui_item,
        const float* __restrict__ ui_w, float* __restrict__ usrNxt) {
    int w = __builtin_amdgcn_readfirstlane(threadIdx.x >> 6);
    int node = blockIdx.x * 4 + w;
    if (node >= NU) return;
    int d = threadIdx.x & 63;
    int b0 = ui_off[node], b1 = ui_off[node + 1];
    float acc = 0.f;
    int s = b0;
    for (; s + 4 <= b1; s += 4) {
        float a0 = ui_w[s + 0] * entCur[(long)ui_item[s + 0] * 64 + d];
        float a1 = ui_w[s + 1] * entCur[(long)ui_item[s + 1] * 64 + d];
        float a2 = ui_w[s + 2] * entCur[(long)ui_item[s + 2] * 64 + d];
        float a3 = ui_w[s + 3] * entCur[(long)ui_item[s + 3] * 64 + d];
        acc += (a0 + a1) + (a2 + a3);
    }
    for (; s < b1; s++)
        acc += ui_w[s] * entCur[(long)ui_item[s] * 64 + d];
    usrNxt[(long)node * 64 + d] = acc;
}

// out = concat(mean(usr0..2), mean(ent0..2))
__global__ void k_final(const float* __restrict__ u0, const float* __restrict__ u1,
                        const float* __restrict__ u2, const float* __restrict__ e0,
                        const float* __restrict__ e1, const float* __restrict__ e2,
                        float* __restrict__ out) {
    int i = blockIdx.x * blockDim.x + threadIdx.x;
    const float inv3 = 1.f / 3.f;
    if (i < NU * DIM) {
        out[i] = (u0[i] + u1[i] + u2[i]) * inv3;
    } else if (i < (NU + NE) * DIM) {
        int j = i - NU * DIM;
        out[i] = (e0[j] + e1[j] + e2[j]) * inv3;
    }
}

extern "C" void kernel_launch(void* const* d_in, const int* in_sizes, int n_in,
                              void* d_out, int out_size, void* d_ws, size_t ws_size,
                              hipStream_t stream) {
    const float* usr0  = (const float*)d_in[1];   // [NU, 64]
    const float* ent0  = (const float*)d_in[2];   // [NE, 64]
    const int*   inter = (const int*)d_in[3];     // [2, EIN]
    const float* iwf   = (const float*)d_in[4];   // [EIN]
    const int*   eidx  = (const int*)d_in[5];     // [2, EKG]
    const int*   etype = (const int*)d_in[6];     // [EKG]
    const float* relf  = (const float*)d_in[7];   // [16, 64]
    const float* wqf   = (const float*)d_in[8];   // [64, 64]
    float* out = (float*)d_out;

    const int* eh = eidx;
    const int* et = eidx + EKG;
    const int* iu = inter;
    const int* ii = inter + EIN;

    // ---- workspace layout (4B words), ~127 MB total ----
    float* p = (float*)d_ws;
    float* qm   = p;  p += (long)NE * DIM;
    float* ent1 = p;  p += (long)NE * DIM;
    float* ent2 = p;  p += (long)NE * DIM;
    float* usr1 = p;  p += (long)NU * DIM;
    float* usr2 = p;  p += (long)NU * DIM;
    int* kg_cnt = (int*)p;      p += NE;
    int* kg_off = (int*)p;      p += NE + 1;
    int* kg_cur = (int*)p;      p += NE;
    int* ui_cnt = (int*)p;      p += NU;
    int* ui_off = (int*)p;      p += NU + 1;
    int* ui_cur = (int*)p;      p += NU;
    int* iu_cnt = (int*)p;      p += NE;
    int* iu_off = (int*)p;      p += NE + 1;
    int* iu_cur = (int*)p;      p += NE;
    unsigned* kg_tr = (unsigned*)p; p += EKG;
    int* ui_item = (int*)p;     p += EIN;
    float* ui_w  = p;           p += EIN;
    int* iu_user = (int*)p;     p += EIN;
    float* iu_wv = p;           p += EIN;

    const int B = 256;
    // ---- CSR build (once per call) ----
    hipMemsetAsync(kg_cnt, 0, NE * 4, stream);
    hipMemsetAsync(ui_cnt, 0, NU * 4, stream);
    hipMemsetAsync(iu_cnt, 0, NE * 4, stream);
    int gEdge = (EKG + B - 1) / B;
    k_hist<<<gEdge, B, 0, stream>>>(eh, iu, ii, kg_cnt, ui_cnt, iu_cnt);
    k_scan<<<1, 1024, 0, stream>>>(kg_cnt, kg_off, kg_cur, NE);
    k_scan<<<1, 1024, 0, stream>>>(ui_cnt, ui_off, ui_cur, NU);
    k_scan<<<1, 1024, 0, stream>>>(iu_cnt, iu_off, iu_cur, NE);
    k_scatter<<<gEdge, B, 0, stream>>>(eh, et, etype, iu, ii, iwf,
                                       kg_cur, kg_tr, ui_cur, ui_item, ui_w,
                                       iu_cur, iu_user, iu_wv);

    const float* entBuf[3] = {ent0, ent1, ent2};
    const float* usrBuf[3] = {usr0, usr1, usr2};

    for (int L = 0; L < 2; L++) {
        const float* entCur = entBuf[L];
        const float* usrCur = usrBuf[L];
        float* entNxt = (float*)entBuf[L + 1];
        float* usrNxt = (float*)usrBuf[L + 1];

        k_gemm<<<NE / 4, 256, 0, stream>>>(entCur, wqf, qm, NE);
        k_ent<<<(NE + 3) / 4, 256, 0, stream>>>(qm, relf, entCur, usrCur,
                                                kg_off, kg_tr, iu_off, iu_user,
                                                iu_wv, entNxt);
        k_usr<<<(NU + 3) / 4, 256, 0, stream>>>(entCur, ui_off, ui_item, ui_w, usrNxt);
    }

    k_final<<<((NU + NE) * DIM + B - 1) / B, B, 0, stream>>>(usr0, usr1, usr2,
                                                             ent0, ent1, ent2, out);
}

// Round 6
// 937.361 us; speedup vs baseline: 2.7125x; 1.6014x over previous
//
#include <hip/hip_runtime.h>

#define NU 50000
#define NE 100000
#define DIM 64
#define NRELS 16
#define EKG 1500000
#define EIN 1000000

// qm[i][c] = sum_k ent[i][k] * WQ[k][c]   (4 rows per 256-thread block)
__global__ __launch_bounds__(256) void k_gemm(const float* __restrict__ ent,
                                              const float* __restrict__ wq,
                                              float* __restrict__ qm, int nrows) {
    __shared__ float sW[64 * 64];
    __shared__ float sR[4][64];
    int t = threadIdx.x;
    for (int i = t; i < 4096; i += 256) sW[i] = wq[i];
    int r = t >> 6, c = t & 63;
    int row = blockIdx.x * 4 + r;
    sR[r][c] = (row < nrows) ? ent[row * 64 + c] : 0.f;
    __syncthreads();
    float acc = 0.f;
#pragma unroll
    for (int k = 0; k < 64; k++) acc += sR[r][k] * sW[k * 64 + c];
    if (row < nrows) qm[row * 64 + c] = acc;
}

// histogram for the three CSRs
__global__ void k_hist(const int* __restrict__ eh, const int* __restrict__ iu,
                       const int* __restrict__ ii, int* kg_cnt, int* ui_cnt, int* iu_cnt) {
    int e = blockIdx.x * blockDim.x + threadIdx.x;
    if (e < EKG) atomicAdd(&kg_cnt[eh[e]], 1);
    if (e < EIN) { atomicAdd(&ui_cnt[iu[e]], 1); atomicAdd(&iu_cnt[ii[e]], 1); }
}

// ---- hierarchical scan ----
// P1: per-block (1024 elems) sums
__global__ __launch_bounds__(256) void k_scan_p1(const int* __restrict__ cnt, int n,
                                                 int* __restrict__ partials) {
    int t = threadIdx.x;
    int i0 = blockIdx.x * 1024 + t * 4;
    int s = 0;
    if (i0 + 3 < n) {
        int4 v = *(const int4*)(cnt + i0);
        s = v.x + v.y + v.z + v.w;
    } else {
        for (int j = 0; j < 4; j++) if (i0 + j < n) s += cnt[i0 + j];
    }
    for (int o = 1; o < 64; o <<= 1) s += __shfl_xor(s, o, 64);
    __shared__ int ws[4];
    if ((t & 63) == 0) ws[t >> 6] = s;
    __syncthreads();
    if (t == 0) partials[blockIdx.x] = ws[0] + ws[1] + ws[2] + ws[3];
}

// P2: one wave per array scans its partials in place (exclusive), writes off[n]
__global__ __launch_bounds__(64) void k_scan_p2(int* p0, int n0, int* t0,
                                                int* p1, int n1, int* t1,
                                                int* p2, int n2, int* t2) {
    int* part; int nb; int* offn;
    if (blockIdx.x == 0) { part = p0; nb = n0; offn = t0; }
    else if (blockIdx.x == 1) { part = p1; nb = n1; offn = t1; }
    else { part = p2; nb = n2; offn = t2; }
    int lane = threadIdx.x;
    int run = 0;
    for (int base = 0; base < nb; base += 64) {
        int i = base + lane;
        int v = (i < nb) ? part[i] : 0;
        int incl = v;
        for (int o = 1; o < 64; o <<= 1) {
            int u = __shfl_up(incl, o, 64);
            if (lane >= o) incl += u;
        }
        if (i < nb) part[i] = run + (incl - v);
        run += __shfl(incl, 63, 64);
    }
    if (lane == 0) *offn = run;
}

// P3: block-local exclusive scan + base -> off/cur
__global__ __launch_bounds__(256) void k_scan_p3(const int* __restrict__ cnt, int n,
                                                 const int* __restrict__ partials,
                                                 int* __restrict__ off,
                                                 int* __restrict__ cur) {
    int t = threadIdx.x;
    int lane = t & 63, w = t >> 6;
    int i0 = blockIdx.x * 1024 + t * 4;
    int vals[4];
    int s = 0;
    if (i0 + 3 < n) {
        int4 v = *(const int4*)(cnt + i0);
        vals[0] = v.x; vals[1] = v.y; vals[2] = v.z; vals[3] = v.w;
        s = v.x + v.y + v.z + v.w;
    } else {
#pragma unroll
        for (int j = 0; j < 4; j++) { vals[j] = (i0 + j < n) ? cnt[i0 + j] : 0; s += vals[j]; }
    }
    int incl = s;
    for (int o = 1; o < 64; o <<= 1) {
        int u = __shfl_up(incl, o, 64);
        if (lane >= o) incl += u;
    }
    int excl = incl - s;
    __shared__ int wsum[4];
    if (lane == 63) wsum[w] = incl;
    __syncthreads();
    int wbase = 0;
    for (int j = 0; j < w; j++) wbase += wsum[j];
    int run = partials[blockIdx.x] + wbase + excl;
#pragma unroll
    for (int j = 0; j < 4; j++) {
        int i = i0 + j;
        if (i < n) { off[i] = run; cur[i] = run; }
        run += vals[j];
    }
}

// scatter edges into CSR slots
__global__ void k_scatter(const int* __restrict__ eh, const int* __restrict__ et,
                          const int* __restrict__ ety, const int* __restrict__ iu,
                          const int* __restrict__ ii, const float* __restrict__ iw,
                          int* kg_cur, unsigned* __restrict__ kg_tr,
                          int* ui_cur, int* __restrict__ ui_item, float* __restrict__ ui_w,
                          int* iu_cur, int* __restrict__ iu_user, float* __restrict__ iu_wv) {
    int e = blockIdx.x * blockDim.x + threadIdx.x;
    if (e < EKG) {
        int pos = atomicAdd(&kg_cur[eh[e]], 1);
        kg_tr[pos] = (unsigned)et[e] | ((unsigned)(ety[e] - 1) << 17);
    }
    if (e < EIN) {
        int u = iu[e], it = ii[e]; float w = iw[e];
        int p1 = atomicAdd(&ui_cur[u], 1); ui_item[p1] = it; ui_w[p1] = w;
        int p2 = atomicAdd(&iu_cur[it], 1); iu_user[p2] = u; iu_wv[p2] = w;
    }
}

#define SHFL_RED(p) \
    p += __shfl_xor(p, 16, 64); p += __shfl_xor(p, 8, 64); \
    p += __shfl_xor(p, 4, 64);  p += __shfl_xor(p, 2, 64); \
    p += __shfl_xor(p, 1, 64);

// fused per-node entity aggregation: single-pass online softmax + weighted
// gather + L2 normalize + user->entity gather. One wave per node, lane = dim.
__global__ __launch_bounds__(256) void k_ent(const float* __restrict__ qm,
        const float* __restrict__ relf, const float* __restrict__ entCur,
        const float* __restrict__ usrCur,
        const int* __restrict__ kg_off, const unsigned* __restrict__ kg_tr,
        const int* __restrict__ iu_off, const int* __restrict__ iu_user,
        const float* __restrict__ iu_w, float* __restrict__ entNxt) {
    int w = __builtin_amdgcn_readfirstlane(threadIdx.x >> 6);
    int node = blockIdx.x * 4 + w;
    if (node >= NE) return;
    int d = threadIdx.x & 63;
    const float SC = 0.17677669529663687f; // 1/sqrt(32)
    float qh = qm[(long)node * 64 + d];
    int b0 = kg_off[node], b1 = kg_off[node + 1];
    int deg = b1 - b0;

    float m = -INFINITY, ssum = 0.f, acc = 0.f;
    int s = b0;
    for (; s + 4 <= b1; s += 4) {
        float sc[4], val[4];
#pragma unroll
        for (int j = 0; j < 4; j++) {
            unsigned tr = kg_tr[s + j];
            int tl = tr & 0x1FFFF, rr = tr >> 17;
            float rl = relf[rr * 64 + d];
            float qt = qm[(long)tl * 64 + d];
            val[j] = entCur[(long)tl * 64 + d] * rl;
            float p = qh * qt * rl;
            SHFL_RED(p)
            sc[j] = p * SC;
        }
        float cmax = fmaxf(fmaxf(sc[0], sc[1]), fmaxf(sc[2], sc[3]));
        float mn = fmaxf(m, cmax);
        float scale = __expf(m - mn); // first chunk: exp(-inf)=0
        ssum *= scale; acc *= scale;
#pragma unroll
        for (int j = 0; j < 4; j++) {
            float e = __expf(sc[j] - mn);
            ssum += e;
            acc += val[j] * e;
        }
        m = mn;
    }
    for (; s < b1; s++) {
        unsigned tr = kg_tr[s];
        int tl = tr & 0x1FFFF, rr = tr >> 17;
        float rl = relf[rr * 64 + d];
        float qt = qm[(long)tl * 64 + d];
        float v = entCur[(long)tl * 64 + d] * rl;
        float p = qh * qt * rl;
        SHFL_RED(p)
        float scv = p * SC;
        float mn = fmaxf(m, scv);
        float scale = __expf(m - mn);
        float e = __expf(scv - mn);
        ssum = ssum * scale + e;
        acc = acc * scale + v * e;
        m = mn;
    }
    if (deg > 0) acc /= ssum;

    // L2 normalize across the 64-dim row
    float ss = acc * acc;
    SHFL_RED(ss)
    ss += __shfl_xor(ss, 32, 64);
    float scale = 1.f / fmaxf(sqrtf(ss), 1e-12f);
    acc *= scale;

    // + user -> entity contributions (x4 unrolled gather)
    int c0 = iu_off[node], c1 = iu_off[node + 1];
    int t = c0;
    for (; t + 4 <= c1; t += 4) {
        float a0 = iu_w[t + 0] * usrCur[(long)iu_user[t + 0] * 64 + d];
        float a1 = iu_w[t + 1] * usrCur[(long)iu_user[t + 1] * 64 + d];
        float a2 = iu_w[t + 2] * usrCur[(long)iu_user[t + 2] * 64 + d];
        float a3 = iu_w[t + 3] * usrCur[(long)iu_user[t + 3] * 64 + d];
        acc += (a0 + a1) + (a2 + a3);
    }
    for (; t < c1; t++)
        acc += iu_w[t] * usrCur[(long)iu_user[t] * 64 + d];
    entNxt[(long)node * 64 + d] = acc;
}

// user <- item gather (x4 unrolled)
__global__ __launch_bounds__(256) void k_usr(const float* __restrict__ entCur,
        const int* __restrict__ ui_off, const int* __restrict__ ui_item,
        const float* __restrict__ ui_w, float* __restrict__ usrNxt) {
    int w = __builtin_amdgcn_readfirstlane(threadIdx.x >> 6);
    int node = blockIdx.x * 4 + w;
    if (node >= NU) return;
    int d = threadIdx.x & 63;
    int b0 = ui_off[node], b1 = ui_off[node + 1];
    float acc = 0.f;
    int s = b0;
    for (; s + 4 <= b1; s += 4) {
        float a0 = ui_w[s + 0] * entCur[(long)ui_item[s + 0] * 64 + d];
        float a1 = ui_w[s + 1] * entCur[(long)ui_item[s + 1] * 64 + d];
        float a2 = ui_w[s + 2] * entCur[(long)ui_item[s + 2] * 64 + d];
        float a3 = ui_w[s + 3] * entCur[(long)ui_item[s + 3] * 64 + d];
        acc += (a0 + a1) + (a2 + a3);
    }
    for (; s < b1; s++)
        acc += ui_w[s] * entCur[(long)ui_item[s] * 64 + d];
    usrNxt[(long)node * 64 + d] = acc;
}

// out = concat(mean(usr0..2), mean(ent0..2))
__global__ void k_final(const float* __restrict__ u0, const float* __restrict__ u1,
                        const float* __restrict__ u2, const float* __restrict__ e0,
                        const float* __restrict__ e1, const float* __restrict__ e2,
                        float* __restrict__ out) {
    int i = blockIdx.x * blockDim.x + threadIdx.x;
    const float inv3 = 1.f / 3.f;
    if (i < NU * DIM) {
        out[i] = (u0[i] + u1[i] + u2[i]) * inv3;
    } else if (i < (NU + NE) * DIM) {
        int j = i - NU * DIM;
        out[i] = (e0[j] + e1[j] + e2[j]) * inv3;
    }
}

extern "C" void kernel_launch(void* const* d_in, const int* in_sizes, int n_in,
                              void* d_out, int out_size, void* d_ws, size_t ws_size,
                              hipStream_t stream) {
    const float* usr0  = (const float*)d_in[1];   // [NU, 64]
    const float* ent0  = (const float*)d_in[2];   // [NE, 64]
    const int*   inter = (const int*)d_in[3];     // [2, EIN]
    const float* iwf   = (const float*)d_in[4];   // [EIN]
    const int*   eidx  = (const int*)d_in[5];     // [2, EKG]
    const int*   etype = (const int*)d_in[6];     // [EKG]
    const float* relf  = (const float*)d_in[7];   // [16, 64]
    const float* wqf   = (const float*)d_in[8];   // [64, 64]
    float* out = (float*)d_out;

    const int* eh = eidx;
    const int* et = eidx + EKG;
    const int* iu = inter;
    const int* ii = inter + EIN;

    // ---- workspace layout (4B words), ~127 MB total ----
    float* p = (float*)d_ws;
    float* qm   = p;  p += (long)NE * DIM;
    float* ent1 = p;  p += (long)NE * DIM;
    float* ent2 = p;  p += (long)NE * DIM;
    float* usr1 = p;  p += (long)NU * DIM;
    float* usr2 = p;  p += (long)NU * DIM;
    // three cnt arrays contiguous -> one memset
    int* kg_cnt = (int*)p;      p += NE;
    int* ui_cnt = (int*)p;      p += NU;
    int* iu_cnt = (int*)p;      p += NE;
    int* kg_off = (int*)p;      p += NE + 1;
    int* kg_cur = (int*)p;      p += NE;
    int* ui_off = (int*)p;      p += NU + 1;
    int* ui_cur = (int*)p;      p += NU;
    int* iu_off = (int*)p;      p += NE + 1;
    int* iu_cur = (int*)p;      p += NE;
    unsigned* kg_tr = (unsigned*)p; p += EKG;
    int* ui_item = (int*)p;     p += EIN;
    float* ui_w  = p;           p += EIN;
    int* iu_user = (int*)p;     p += EIN;
    float* iu_wv = p;           p += EIN;
    int* pk = (int*)p;          p += 128;   // scan partials
    int* pu = (int*)p;          p += 128;
    int* pi = (int*)p;          p += 128;

    const int B = 256;
    const int NBK = (NE + 1023) / 1024;   // 98
    const int NBU = (NU + 1023) / 1024;   // 49

    // ---- CSR build (once per call) ----
    hipMemsetAsync(kg_cnt, 0, (size_t)(NE + NU + NE) * 4, stream);
    int gEdge = (EKG + B - 1) / B;
    k_hist<<<gEdge, B, 0, stream>>>(eh, iu, ii, kg_cnt, ui_cnt, iu_cnt);
    k_scan_p1<<<NBK, 256, 0, stream>>>(kg_cnt, NE, pk);
    k_scan_p1<<<NBU, 256, 0, stream>>>(ui_cnt, NU, pu);
    k_scan_p1<<<NBK, 256, 0, stream>>>(iu_cnt, NE, pi);
    k_scan_p2<<<3, 64, 0, stream>>>(pk, NBK, kg_off + NE,
                                    pu, NBU, ui_off + NU,
                                    pi, NBK, iu_off + NE);
    k_scan_p3<<<NBK, 256, 0, stream>>>(kg_cnt, NE, pk, kg_off, kg_cur);
    k_scan_p3<<<NBU, 256, 0, stream>>>(ui_cnt, NU, pu, ui_off, ui_cur);
    k_scan_p3<<<NBK, 256, 0, stream>>>(iu_cnt, NE, pi, iu_off, iu_cur);
    k_scatter<<<gEdge, B, 0, stream>>>(eh, et, etype, iu, ii, iwf,
                                       kg_cur, kg_tr, ui_cur, ui_item, ui_w,
                                       iu_cur, iu_user, iu_wv);

    const float* entBuf[3] = {ent0, ent1, ent2};
    const float* usrBuf[3] = {usr0, usr1, usr2};

    for (int L = 0; L < 2; L++) {
        const float* entCur = entBuf[L];
        const float* usrCur = usrBuf[L];
        float* entNxt = (float*)entBuf[L + 1];
        float* usrNxt = (float*)usrBuf[L + 1];

        k_gemm<<<NE / 4, 256, 0, stream>>>(entCur, wqf, qm, NE);
        k_ent<<<(NE + 3) / 4, 256, 0, stream>>>(qm, relf, entCur, usrCur,
                                                kg_off, kg_tr, iu_off, iu_user,
                                                iu_wv, entNxt);
        k_usr<<<(NU + 3) / 4, 256, 0, stream>>>(entCur, ui_off, ui_item, ui_w, usrNxt);
    }

    k_final<<<((NU + NE) * DIM + B - 1) / B, B, 0, stream>>>(usr0, usr1, usr2,
                                                             ent0, ent1, ent2, out);
}

// Round 7
// 844.799 us; speedup vs baseline: 3.0097x; 1.1096x over previous
//
#include <hip/hip_runtime.h>

#define NU 50000
#define NE 100000
#define DIM 64
#define NRELS 16
#define EKG 1500000
#define EIN 1000000

#define KG_CHUNK 8192
#define KG_NBUCK ((NE + 511) >> 9)   // 196
#define B8_CHUNK 4096
#define KG_CAP 9216                  // Binomial mean 7680, sigma 87 -> +17s
#define C8_CAP 6656                  // mean 5120, sigma 71 -> +21s

// qm[i][c] = sum_k ent[i][k] * WQ[k][c]   (4 rows per 256-thread block)
__global__ __launch_bounds__(256) void k_gemm(const float* __restrict__ ent,
                                              const float* __restrict__ wq,
                                              float* __restrict__ qm, int nrows) {
    __shared__ float sW[64 * 64];
    __shared__ float sR[4][64];
    int t = threadIdx.x;
    for (int i = t; i < 4096; i += 256) sW[i] = wq[i];
    int r = t >> 6, c = t & 63;
    int row = blockIdx.x * 4 + r;
    sR[r][c] = (row < nrows) ? ent[row * 64 + c] : 0.f;
    __syncthreads();
    float acc = 0.f;
#pragma unroll
    for (int k = 0; k < 64; k++) acc += sR[r][k] * sW[k * 64 + c];
    if (row < nrows) qm[row * 64 + c] = acc;
}

// histogram for the three CSRs
__global__ void k_hist(const int* __restrict__ eh, const int* __restrict__ iu,
                       const int* __restrict__ ii, int* kg_cnt, int* ui_cnt, int* iu_cnt) {
    int e = blockIdx.x * blockDim.x + threadIdx.x;
    if (e < EKG) atomicAdd(&kg_cnt[eh[e]], 1);
    if (e < EIN) { atomicAdd(&ui_cnt[iu[e]], 1); atomicAdd(&iu_cnt[ii[e]], 1); }
}

// ---- hierarchical scan ----
__global__ __launch_bounds__(256) void k_scan_p1(const int* __restrict__ cnt, int n,
                                                 int* __restrict__ partials) {
    int t = threadIdx.x;
    int i0 = blockIdx.x * 1024 + t * 4;
    int s = 0;
    if (i0 + 3 < n) {
        int4 v = *(const int4*)(cnt + i0);
        s = v.x + v.y + v.z + v.w;
    } else {
        for (int j = 0; j < 4; j++) if (i0 + j < n) s += cnt[i0 + j];
    }
    for (int o = 1; o < 64; o <<= 1) s += __shfl_xor(s, o, 64);
    __shared__ int ws[4];
    if ((t & 63) == 0) ws[t >> 6] = s;
    __syncthreads();
    if (t == 0) partials[blockIdx.x] = ws[0] + ws[1] + ws[2] + ws[3];
}

__global__ __launch_bounds__(64) void k_scan_p2(int* p0, int n0, int* t0,
                                                int* p1, int n1, int* t1,
                                                int* p2, int n2, int* t2) {
    int* part; int nb; int* offn;
    if (blockIdx.x == 0) { part = p0; nb = n0; offn = t0; }
    else if (blockIdx.x == 1) { part = p1; nb = n1; offn = t1; }
    else { part = p2; nb = n2; offn = t2; }
    int lane = threadIdx.x;
    int run = 0;
    for (int base = 0; base < nb; base += 64) {
        int i = base + lane;
        int v = (i < nb) ? part[i] : 0;
        int incl = v;
        for (int o = 1; o < 64; o <<= 1) {
            int u = __shfl_up(incl, o, 64);
            if (lane >= o) incl += u;
        }
        if (i < nb) part[i] = run + (incl - v);
        run += __shfl(incl, 63, 64);
    }
    if (lane == 0) *offn = run;
}

__global__ __launch_bounds__(256) void k_scan_p3(const int* __restrict__ cnt, int n,
                                                 const int* __restrict__ partials,
                                                 int* __restrict__ off) {
    int t = threadIdx.x;
    int lane = t & 63, w = t >> 6;
    int i0 = blockIdx.x * 1024 + t * 4;
    int vals[4];
    int s = 0;
    if (i0 + 3 < n) {
        int4 v = *(const int4*)(cnt + i0);
        vals[0] = v.x; vals[1] = v.y; vals[2] = v.z; vals[3] = v.w;
        s = v.x + v.y + v.z + v.w;
    } else {
#pragma unroll
        for (int j = 0; j < 4; j++) { vals[j] = (i0 + j < n) ? cnt[i0 + j] : 0; s += vals[j]; }
    }
    int incl = s;
    for (int o = 1; o < 64; o <<= 1) {
        int u = __shfl_up(incl, o, 64);
        if (lane >= o) incl += u;
    }
    int excl = incl - s;
    __shared__ int wsum[4];
    if (lane == 63) wsum[w] = incl;
    __syncthreads();
    int wbase = 0;
    for (int j = 0; j < w; j++) wbase += wsum[j];
    int run = partials[blockIdx.x] + wbase + excl;
#pragma unroll
    for (int j = 0; j < 4; j++) {
        int i = i0 + j;
        if (i < n) off[i] = run;
        run += vals[j];
    }
}

// init per-bucket global cursors from off arrays
__global__ void k_initgcur(const int* __restrict__ kg_off, const int* __restrict__ ui_off,
                           const int* __restrict__ iu_off,
                           int* kg_g, int* ui_g, int* iu_g) {
    int b = threadIdx.x;  // 256
    int a = b << 9; if (a > NE) a = NE;
    kg_g[b] = kg_off[a];
    iu_g[b] = iu_off[a];
    int c = b << 8; if (c > NU) c = NU;
    ui_g[b] = ui_off[c];
}

// ---- pass B: bin KG edges into node-range buckets (LDS staged, coalesced flush)
__global__ __launch_bounds__(256) void k_binB_kg(const int* __restrict__ eh,
        const int* __restrict__ et, const int* __restrict__ ety,
        int* __restrict__ gcur, unsigned* __restrict__ tmp) {
    __shared__ unsigned stage[KG_CHUNK];
    __shared__ int dest[KG_CHUNK];
    __shared__ int cnt[KG_NBUCK], boff[KG_NBUCK], gbase[KG_NBUCK], curl[KG_NBUCK];
    __shared__ int sc[256];
    int t = threadIdx.x;
    int base = blockIdx.x * KG_CHUNK;
    int nloc = EKG - base; if (nloc > KG_CHUNK) nloc = KG_CHUNK;
    for (int i = t; i < KG_NBUCK; i += 256) cnt[i] = 0;
    __syncthreads();
    for (int i = t; i < nloc; i += 256)
        atomicAdd(&cnt[eh[base + i] >> 9], 1);
    __syncthreads();
    int v = (t < KG_NBUCK) ? cnt[t] : 0;
    sc[t] = v;
    __syncthreads();
    for (int o = 1; o < 256; o <<= 1) {
        int u = (t >= o) ? sc[t - o] : 0;
        __syncthreads();
        sc[t] += u;
        __syncthreads();
    }
    if (t < KG_NBUCK) {
        boff[t] = sc[t] - v;
        curl[t] = sc[t] - v;
        gbase[t] = atomicAdd(&gcur[t], v);
    }
    __syncthreads();
    for (int i = t; i < nloc; i += 256) {
        int e = base + i;
        int h = eh[e];
        int b = h >> 9;
        unsigned pay = (unsigned)et[e] | ((unsigned)(ety[e] - 1) << 17)
                     | ((unsigned)(h & 511) << 21);
        int pos = atomicAdd(&curl[b], 1);
        stage[pos] = pay;
        dest[pos] = gbase[b] + (pos - boff[b]);
    }
    __syncthreads();
    for (int s = t; s < nloc; s += 256) tmp[dest[s]] = stage[s];
}

// ---- pass B generic, 8B payload {aux|low<<auxShift, w}
__global__ __launch_bounds__(256) void k_binB8(const int* __restrict__ key,
        const int* __restrict__ aux, const float* __restrict__ wv, int nE,
        int shift, int auxShift, int* __restrict__ gcur, int2* __restrict__ tmp) {
    __shared__ int2 stage[B8_CHUNK];
    __shared__ int dest[B8_CHUNK];
    __shared__ int cnt[256], boff[256], gbase[256], curl[256];
    __shared__ int sc[256];
    int t = threadIdx.x;
    int base = blockIdx.x * B8_CHUNK;
    int nloc = nE - base; if (nloc > B8_CHUNK) nloc = B8_CHUNK;
    cnt[t] = 0;
    __syncthreads();
    for (int i = t; i < nloc; i += 256)
        atomicAdd(&cnt[key[base + i] >> shift], 1);
    __syncthreads();
    int v = cnt[t];
    sc[t] = v;
    __syncthreads();
    for (int o = 1; o < 256; o <<= 1) {
        int u = (t >= o) ? sc[t - o] : 0;
        __syncthreads();
        sc[t] += u;
        __syncthreads();
    }
    boff[t] = sc[t] - v;
    curl[t] = sc[t] - v;
    gbase[t] = atomicAdd(&gcur[t], v);   // v=0 for unused buckets
    __syncthreads();
    int lowmask = (1 << shift) - 1;
    for (int i = t; i < nloc; i += 256) {
        int e = base + i;
        int k = key[e];
        int b = k >> shift;
        int2 pay;
        pay.x = aux[e] | ((k & lowmask) << auxShift);
        pay.y = __float_as_int(wv[e]);
        int pos = atomicAdd(&curl[b], 1);
        stage[pos] = pay;
        dest[pos] = gbase[b] + (pos - boff[b]);
    }
    __syncthreads();
    for (int s = t; s < nloc; s += 256) tmp[dest[s]] = stage[s];
}

// ---- pass C: within-bucket counting sort into final CSR (LDS staged)
__global__ __launch_bounds__(256) void k_binC_kg(const unsigned* __restrict__ tmp,
        const int* __restrict__ off, unsigned* __restrict__ dst) {
    __shared__ unsigned stage[KG_CAP];
    __shared__ int curl[512];
    int b = blockIdx.x;
    int nbase = b << 9;
    int nlim = NE - nbase; if (nlim > 512) nlim = 512;
    if (nlim <= 0) return;
    int t = threadIdx.x;
    int r0 = off[nbase];
    int r1 = off[nbase + nlim];
    int cntb = r1 - r0;
    for (int i = t; i < nlim; i += 256) curl[i] = off[nbase + i] - r0;
    __syncthreads();
    if (cntb <= KG_CAP) {
        for (int s = t; s < cntb; s += 256) {
            unsigned pay = tmp[r0 + s];
            int l = (pay >> 21) & 511;
            int pos = atomicAdd(&curl[l], 1);
            stage[pos] = pay;
        }
        __syncthreads();
        for (int s = t; s < cntb; s += 256) dst[r0 + s] = stage[s];
    } else { // fallback: direct (region stays L2-resident anyway)
        for (int s = t; s < cntb; s += 256) {
            unsigned pay = tmp[r0 + s];
            int l = (pay >> 21) & 511;
            int pos = atomicAdd(&curl[l], 1);
            dst[r0 + pos] = pay;
        }
    }
}

__global__ __launch_bounds__(256) void k_binC8(const int2* __restrict__ tmp,
        const int* __restrict__ off, int2* __restrict__ dst, int nnodes,
        int shift, int auxShift) {
    __shared__ int2 stage[C8_CAP];
    __shared__ int curl[512];
    int b = blockIdx.x;
    int nbase = b << shift;
    int nlim = nnodes - nbase; if (nlim > (1 << shift)) nlim = 1 << shift;
    if (nlim <= 0) return;
    int t = threadIdx.x;
    int r0 = off[nbase];
    int r1 = off[nbase + nlim];
    int cntb = r1 - r0;
    int lowmask = (1 << shift) - 1;
    for (int i = t; i < nlim; i += 256) curl[i] = off[nbase + i] - r0;
    __syncthreads();
    if (cntb <= C8_CAP) {
        for (int s = t; s < cntb; s += 256) {
            int2 pay = tmp[r0 + s];
            int l = (pay.x >> auxShift) & lowmask;
            int pos = atomicAdd(&curl[l], 1);
            stage[pos] = pay;
        }
        __syncthreads();
        for (int s = t; s < cntb; s += 256) dst[r0 + s] = stage[s];
    } else {
        for (int s = t; s < cntb; s += 256) {
            int2 pay = tmp[r0 + s];
            int l = (pay.x >> auxShift) & lowmask;
            int pos = atomicAdd(&curl[l], 1);
            dst[r0 + pos] = pay;
        }
    }
}

#define SHFL_RED(p) \
    p += __shfl_xor(p, 16, 64); p += __shfl_xor(p, 8, 64); \
    p += __shfl_xor(p, 4, 64);  p += __shfl_xor(p, 2, 64); \
    p += __shfl_xor(p, 1, 64);

// fused per-node entity aggregation
__global__ __launch_bounds__(256) void k_ent(const float* __restrict__ qm,
        const float* __restrict__ relf, const float* __restrict__ entCur,
        const float* __restrict__ usrCur,
        const int* __restrict__ kg_off, const unsigned* __restrict__ kg_tr,
        const int* __restrict__ iu_off, const int2* __restrict__ iu_iw,
        float* __restrict__ entNxt) {
    int w = __builtin_amdgcn_readfirstlane(threadIdx.x >> 6);
    int node = blockIdx.x * 4 + w;
    if (node >= NE) return;
    int d = threadIdx.x & 63;
    const float SC = 0.17677669529663687f; // 1/sqrt(32)
    float qh = qm[(long)node * 64 + d];
    int b0 = kg_off[node], b1 = kg_off[node + 1];
    int deg = b1 - b0;

    float m = -INFINITY, ssum = 0.f, acc = 0.f;
    int s = b0;
    for (; s + 4 <= b1; s += 4) {
        float sc[4], val[4];
#pragma unroll
        for (int j = 0; j < 4; j++) {
            unsigned tr = kg_tr[s + j];
            int tl = tr & 0x1FFFF, rr = (tr >> 17) & 15;
            float rl = relf[rr * 64 + d];
            float qt = qm[(long)tl * 64 + d];
            val[j] = entCur[(long)tl * 64 + d] * rl;
            float p = qh * qt * rl;
            SHFL_RED(p)
            sc[j] = p * SC;
        }
        float cmax = fmaxf(fmaxf(sc[0], sc[1]), fmaxf(sc[2], sc[3]));
        float mn = fmaxf(m, cmax);
        float scale = __expf(m - mn);
        ssum *= scale; acc *= scale;
#pragma unroll
        for (int j = 0; j < 4; j++) {
            float e = __expf(sc[j] - mn);
            ssum += e;
            acc += val[j] * e;
        }
        m = mn;
    }
    for (; s < b1; s++) {
        unsigned tr = kg_tr[s];
        int tl = tr & 0x1FFFF, rr = (tr >> 17) & 15;
        float rl = relf[rr * 64 + d];
        float qt = qm[(long)tl * 64 + d];
        float v = entCur[(long)tl * 64 + d] * rl;
        float p = qh * qt * rl;
        SHFL_RED(p)
        float scv = p * SC;
        float mn = fmaxf(m, scv);
        float scale = __expf(m - mn);
        float e = __expf(scv - mn);
        ssum = ssum * scale + e;
        acc = acc * scale + v * e;
        m = mn;
    }
    if (deg > 0) acc /= ssum;

    float ss = acc * acc;
    SHFL_RED(ss)
    ss += __shfl_xor(ss, 32, 64);
    float scale = 1.f / fmaxf(sqrtf(ss), 1e-12f);
    acc *= scale;

    int c0 = iu_off[node], c1 = iu_off[node + 1];
    int t = c0;
    for (; t + 4 <= c1; t += 4) {
        int2 p0 = iu_iw[t + 0], p1 = iu_iw[t + 1], p2 = iu_iw[t + 2], p3 = iu_iw[t + 3];
        float a0 = __int_as_float(p0.y) * usrCur[(long)(p0.x & 0xFFFF) * 64 + d];
        float a1 = __int_as_float(p1.y) * usrCur[(long)(p1.x & 0xFFFF) * 64 + d];
        float a2 = __int_as_float(p2.y) * usrCur[(long)(p2.x & 0xFFFF) * 64 + d];
        float a3 = __int_as_float(p3.y) * usrCur[(long)(p3.x & 0xFFFF) * 64 + d];
        acc += (a0 + a1) + (a2 + a3);
    }
    for (; t < c1; t++) {
        int2 pw = iu_iw[t];
        acc += __int_as_float(pw.y) * usrCur[(long)(pw.x & 0xFFFF) * 64 + d];
    }
    entNxt[(long)node * 64 + d] = acc;
}

// user <- item gather
__global__ __launch_bounds__(256) void k_usr(const float* __restrict__ entCur,
        const int* __restrict__ ui_off, const int2* __restrict__ ui_iw,
        float* __restrict__ usrNxt) {
    int w = __builtin_amdgcn_readfirstlane(threadIdx.x >> 6);
    int node = blockIdx.x * 4 + w;
    if (node >= NU) return;
    int d = threadIdx.x & 63;
    int b0 = ui_off[node], b1 = ui_off[node + 1];
    float acc = 0.f;
    int s = b0;
    for (; s + 4 <= b1; s += 4) {
        int2 p0 = ui_iw[s + 0], p1 = ui_iw[s + 1], p2 = ui_iw[s + 2], p3 = ui_iw[s + 3];
        float a0 = __int_as_float(p0.y) * entCur[(long)(p0.x & 0x1FFFF) * 64 + d];
        float a1 = __int_as_float(p1.y) * entCur[(long)(p1.x & 0x1FFFF) * 64 + d];
        float a2 = __int_as_float(p2.y) * entCur[(long)(p2.x & 0x1FFFF) * 64 + d];
        float a3 = __int_as_float(p3.y) * entCur[(long)(p3.x & 0x1FFFF) * 64 + d];
        acc += (a0 + a1) + (a2 + a3);
    }
    for (; s < b1; s++) {
        int2 pw = ui_iw[s];
        acc += __int_as_float(pw.y) * entCur[(long)(pw.x & 0x1FFFF) * 64 + d];
    }
    usrNxt[(long)node * 64 + d] = acc;
}

__global__ void k_final(const float* __restrict__ u0, const float* __restrict__ u1,
                        const float* __restrict__ u2, const float* __restrict__ e0,
                        const float* __restrict__ e1, const float* __restrict__ e2,
                        float* __restrict__ out) {
    int i = blockIdx.x * blockDim.x + threadIdx.x;
    const float inv3 = 1.f / 3.f;
    if (i < NU * DIM) {
        out[i] = (u0[i] + u1[i] + u2[i]) * inv3;
    } else if (i < (NU + NE) * DIM) {
        int j = i - NU * DIM;
        out[i] = (e0[j] + e1[j] + e2[j]) * inv3;
    }
}

extern "C" void kernel_launch(void* const* d_in, const int* in_sizes, int n_in,
                              void* d_out, int out_size, void* d_ws, size_t ws_size,
                              hipStream_t stream) {
    const float* usr0  = (const float*)d_in[1];
    const float* ent0  = (const float*)d_in[2];
    const int*   inter = (const int*)d_in[3];
    const float* iwf   = (const float*)d_in[4];
    const int*   eidx  = (const int*)d_in[5];
    const int*   etype = (const int*)d_in[6];
    const float* relf  = (const float*)d_in[7];
    const float* wqf   = (const float*)d_in[8];
    float* out = (float*)d_out;

    const int* eh = eidx;
    const int* et = eidx + EKG;
    const int* iu = inter;
    const int* ii = inter + EIN;

    // ---- workspace layout (4B words), ~149 MB (ws proven >= 158 MB) ----
    float* p = (float*)d_ws;
    float* qm   = p;  p += (long)NE * DIM;
    float* ent1 = p;  p += (long)NE * DIM;
    float* ent2 = p;  p += (long)NE * DIM;
    float* usr1 = p;  p += (long)NU * DIM;
    float* usr2 = p;  p += (long)NU * DIM;
    int* kg_cnt = (int*)p;      p += NE;      // contiguous cnts -> one memset
    int* ui_cnt = (int*)p;      p += NU;
    int* iu_cnt = (int*)p;      p += NE;
    int* kg_off = (int*)p;      p += NE + 2;  // padded even for int2 alignment
    int* ui_off = (int*)p;      p += NU + 2;
    int* iu_off = (int*)p;      p += NE + 2;
    int* kg_g   = (int*)p;      p += 256;
    int* ui_g   = (int*)p;      p += 256;
    int* iu_g   = (int*)p;      p += 256;
    unsigned* kg_tr  = (unsigned*)p; p += EKG;
    unsigned* kg_tmp = (unsigned*)p; p += EKG;
    int2* ui_iw  = (int2*)p;    p += (long)EIN * 2;
    int2* ui_tmp = (int2*)p;    p += (long)EIN * 2;
    int2* iu_iw  = (int2*)p;    p += (long)EIN * 2;
    int2* iu_tmp = (int2*)p;    p += (long)EIN * 2;
    int* pk = (int*)p;          p += 128;
    int* pu = (int*)p;          p += 128;
    int* pi = (int*)p;          p += 128;

    const int B = 256;
    const int NBK = (NE + 1023) / 1024;   // 98
    const int NBU = (NU + 1023) / 1024;   // 49

    // ---- CSR build ----
    hipMemsetAsync(kg_cnt, 0, (size_t)(NE + NU + NE) * 4, stream);
    int gEdge = (EKG + B - 1) / B;
    k_hist<<<gEdge, B, 0, stream>>>(eh, iu, ii, kg_cnt, ui_cnt, iu_cnt);
    k_scan_p1<<<NBK, 256, 0, stream>>>(kg_cnt, NE, pk);
    k_scan_p1<<<NBU, 256, 0, stream>>>(ui_cnt, NU, pu);
    k_scan_p1<<<NBK, 256, 0, stream>>>(iu_cnt, NE, pi);
    k_scan_p2<<<3, 64, 0, stream>>>(pk, NBK, kg_off + NE,
                                    pu, NBU, ui_off + NU,
                                    pi, NBK, iu_off + NE);
    k_scan_p3<<<NBK, 256, 0, stream>>>(kg_cnt, NE, pk, kg_off);
    k_scan_p3<<<NBU, 256, 0, stream>>>(ui_cnt, NU, pu, ui_off);
    k_scan_p3<<<NBK, 256, 0, stream>>>(iu_cnt, NE, pi, iu_off);
    k_initgcur<<<1, 256, 0, stream>>>(kg_off, ui_off, iu_off, kg_g, ui_g, iu_g);
    k_binB_kg<<<(EKG + KG_CHUNK - 1) / KG_CHUNK, 256, 0, stream>>>(eh, et, etype, kg_g, kg_tmp);
    k_binB8<<<(EIN + B8_CHUNK - 1) / B8_CHUNK, 256, 0, stream>>>(iu, ii, iwf, EIN, 8, 17, ui_g, ui_tmp);
    k_binB8<<<(EIN + B8_CHUNK - 1) / B8_CHUNK, 256, 0, stream>>>(ii, iu, iwf, EIN, 9, 16, iu_g, iu_tmp);
    k_binC_kg<<<KG_NBUCK, 256, 0, stream>>>(kg_tmp, kg_off, kg_tr);
    k_binC8<<<(NU + 255) >> 8, 256, 0, stream>>>(ui_tmp, ui_off, ui_iw, NU, 8, 17);
    k_binC8<<<(NE + 511) >> 9, 256, 0, stream>>>(iu_tmp, iu_off, iu_iw, NE, 9, 16);

    const float* entBuf[3] = {ent0, ent1, ent2};
    const float* usrBuf[3] = {usr0, usr1, usr2};

    for (int L = 0; L < 2; L++) {
        const float* entCur = entBuf[L];
        const float* usrCur = usrBuf[L];
        float* entNxt = (float*)entBuf[L + 1];
        float* usrNxt = (float*)usrBuf[L + 1];

        k_gemm<<<NE / 4, 256, 0, stream>>>(entCur, wqf, qm, NE);
        k_ent<<<(NE + 3) / 4, 256, 0, stream>>>(qm, relf, entCur, usrCur,
                                                kg_off, kg_tr, iu_off, iu_iw, entNxt);
        k_usr<<<(NU + 3) / 4, 256, 0, stream>>>(entCur, ui_off, ui_iw, usrNxt);
    }

    k_final<<<((NU + NE) * DIM + B - 1) / B, B, 0, stream>>>(usr0, usr1, usr2,
                                                             ent0, ent1, ent2, out);
}

// Round 8
// 797.916 us; speedup vs baseline: 3.1865x; 1.0588x over previous
//
#include <hip/hip_runtime.h>
#include <hip/hip_fp16.h>

#define NU 50000
#define NE 100000
#define DIM 64
#define NRELS 16
#define EKG 1500000
#define EIN 1000000

#define KG_CHUNK 8192
#define KG_NBUCK ((NE + 511) >> 9)   // 196
#define B8_CHUNK 4096
#define KG_CAP 9216                  // Binomial mean 7680, sigma 87 -> +17s
#define C8_CAP 6656                  // mean 5120, sigma 71 -> +21s

// fp16 mirror cast for layer-0 inputs
__global__ void k_castH(const float* __restrict__ ent0, const float* __restrict__ usr0,
                        __half* __restrict__ entH, __half* __restrict__ usrH) {
    int i = blockIdx.x * blockDim.x + threadIdx.x;
    if (i < NE * DIM) entH[i] = __float2half(ent0[i]);
    if (i < NU * DIM) usrH[i] = __float2half(usr0[i]);
}

// qmH[i][c] = (half) sum_k ent[i][k] * WQ[k][c]  -- f32 input
__global__ __launch_bounds__(256) void k_gemm_f(const float* __restrict__ ent,
                                                const float* __restrict__ wq,
                                                __half* __restrict__ qmH, int nrows) {
    __shared__ float sW[64 * 64];
    __shared__ float sR[4][64];
    int t = threadIdx.x;
    for (int i = t; i < 4096; i += 256) sW[i] = wq[i];
    int r = t >> 6, c = t & 63;
    int row = blockIdx.x * 4 + r;
    sR[r][c] = (row < nrows) ? ent[row * 64 + c] : 0.f;
    __syncthreads();
    float acc = 0.f;
#pragma unroll
    for (int k = 0; k < 64; k++) acc += sR[r][k] * sW[k * 64 + c];
    if (row < nrows) qmH[row * 64 + c] = __float2half(acc);
}

// same, fp16 input
__global__ __launch_bounds__(256) void k_gemm_h(const __half* __restrict__ ent,
                                                const float* __restrict__ wq,
                                                __half* __restrict__ qmH, int nrows) {
    __shared__ float sW[64 * 64];
    __shared__ float sR[4][64];
    int t = threadIdx.x;
    for (int i = t; i < 4096; i += 256) sW[i] = wq[i];
    int r = t >> 6, c = t & 63;
    int row = blockIdx.x * 4 + r;
    sR[r][c] = (row < nrows) ? __half2float(ent[row * 64 + c]) : 0.f;
    __syncthreads();
    float acc = 0.f;
#pragma unroll
    for (int k = 0; k < 64; k++) acc += sR[r][k] * sW[k * 64 + c];
    if (row < nrows) qmH[row * 64 + c] = __float2half(acc);
}

// histogram for the three CSRs
__global__ void k_hist(const int* __restrict__ eh, const int* __restrict__ iu,
                       const int* __restrict__ ii, int* kg_cnt, int* ui_cnt, int* iu_cnt) {
    int e = blockIdx.x * blockDim.x + threadIdx.x;
    if (e < EKG) atomicAdd(&kg_cnt[eh[e]], 1);
    if (e < EIN) { atomicAdd(&ui_cnt[iu[e]], 1); atomicAdd(&iu_cnt[ii[e]], 1); }
}

// ---- hierarchical scan ----
__global__ __launch_bounds__(256) void k_scan_p1(const int* __restrict__ cnt, int n,
                                                 int* __restrict__ partials) {
    int t = threadIdx.x;
    int i0 = blockIdx.x * 1024 + t * 4;
    int s = 0;
    if (i0 + 3 < n) {
        int4 v = *(const int4*)(cnt + i0);
        s = v.x + v.y + v.z + v.w;
    } else {
        for (int j = 0; j < 4; j++) if (i0 + j < n) s += cnt[i0 + j];
    }
    for (int o = 1; o < 64; o <<= 1) s += __shfl_xor(s, o, 64);
    __shared__ int ws[4];
    if ((t & 63) == 0) ws[t >> 6] = s;
    __syncthreads();
    if (t == 0) partials[blockIdx.x] = ws[0] + ws[1] + ws[2] + ws[3];
}

__global__ __launch_bounds__(64) void k_scan_p2(int* p0, int n0, int* t0,
                                                int* p1, int n1, int* t1,
                                                int* p2, int n2, int* t2) {
    int* part; int nb; int* offn;
    if (blockIdx.x == 0) { part = p0; nb = n0; offn = t0; }
    else if (blockIdx.x == 1) { part = p1; nb = n1; offn = t1; }
    else { part = p2; nb = n2; offn = t2; }
    int lane = threadIdx.x;
    int run = 0;
    for (int base = 0; base < nb; base += 64) {
        int i = base + lane;
        int v = (i < nb) ? part[i] : 0;
        int incl = v;
        for (int o = 1; o < 64; o <<= 1) {
            int u = __shfl_up(incl, o, 64);
            if (lane >= o) incl += u;
        }
        if (i < nb) part[i] = run + (incl - v);
        run += __shfl(incl, 63, 64);
    }
    if (lane == 0) *offn = run;
}

__global__ __launch_bounds__(256) void k_scan_p3(const int* __restrict__ cnt, int n,
                                                 const int* __restrict__ partials,
                                                 int* __restrict__ off) {
    int t = threadIdx.x;
    int lane = t & 63, w = t >> 6;
    int i0 = blockIdx.x * 1024 + t * 4;
    int vals[4];
    int s = 0;
    if (i0 + 3 < n) {
        int4 v = *(const int4*)(cnt + i0);
        vals[0] = v.x; vals[1] = v.y; vals[2] = v.z; vals[3] = v.w;
        s = v.x + v.y + v.z + v.w;
    } else {
#pragma unroll
        for (int j = 0; j < 4; j++) { vals[j] = (i0 + j < n) ? cnt[i0 + j] : 0; s += vals[j]; }
    }
    int incl = s;
    for (int o = 1; o < 64; o <<= 1) {
        int u = __shfl_up(incl, o, 64);
        if (lane >= o) incl += u;
    }
    int excl = incl - s;
    __shared__ int wsum[4];
    if (lane == 63) wsum[w] = incl;
    __syncthreads();
    int wbase = 0;
    for (int j = 0; j < w; j++) wbase += wsum[j];
    int run = partials[blockIdx.x] + wbase + excl;
#pragma unroll
    for (int j = 0; j < 4; j++) {
        int i = i0 + j;
        if (i < n) off[i] = run;
        run += vals[j];
    }
}

__global__ void k_initgcur(const int* __restrict__ kg_off, const int* __restrict__ ui_off,
                           const int* __restrict__ iu_off,
                           int* kg_g, int* ui_g, int* iu_g) {
    int b = threadIdx.x;  // 256
    int a = b << 9; if (a > NE) a = NE;
    kg_g[b] = kg_off[a];
    iu_g[b] = iu_off[a];
    int c = b << 8; if (c > NU) c = NU;
    ui_g[b] = ui_off[c];
}

// ---- pass B: bin KG edges into node-range buckets (LDS staged, coalesced flush)
__global__ __launch_bounds__(256) void k_binB_kg(const int* __restrict__ eh,
        const int* __restrict__ et, const int* __restrict__ ety,
        int* __restrict__ gcur, unsigned* __restrict__ tmp) {
    __shared__ unsigned stage[KG_CHUNK];
    __shared__ int dest[KG_CHUNK];
    __shared__ int cnt[KG_NBUCK], boff[KG_NBUCK], gbase[KG_NBUCK], curl[KG_NBUCK];
    __shared__ int sc[256];
    int t = threadIdx.x;
    int base = blockIdx.x * KG_CHUNK;
    int nloc = EKG - base; if (nloc > KG_CHUNK) nloc = KG_CHUNK;
    for (int i = t; i < KG_NBUCK; i += 256) cnt[i] = 0;
    __syncthreads();
    for (int i = t; i < nloc; i += 256)
        atomicAdd(&cnt[eh[base + i] >> 9], 1);
    __syncthreads();
    int v = (t < KG_NBUCK) ? cnt[t] : 0;
    sc[t] = v;
    __syncthreads();
    for (int o = 1; o < 256; o <<= 1) {
        int u = (t >= o) ? sc[t - o] : 0;
        __syncthreads();
        sc[t] += u;
        __syncthreads();
    }
    if (t < KG_NBUCK) {
        boff[t] = sc[t] - v;
        curl[t] = sc[t] - v;
        gbase[t] = atomicAdd(&gcur[t], v);
    }
    __syncthreads();
    for (int i = t; i < nloc; i += 256) {
        int e = base + i;
        int h = eh[e];
        int b = h >> 9;
        unsigned pay = (unsigned)et[e] | ((unsigned)(ety[e] - 1) << 17)
                     | ((unsigned)(h & 511) << 21);
        int pos = atomicAdd(&curl[b], 1);
        stage[pos] = pay;
        dest[pos] = gbase[b] + (pos - boff[b]);
    }
    __syncthreads();
    for (int s = t; s < nloc; s += 256) tmp[dest[s]] = stage[s];
}

// ---- pass B generic, 8B payload {aux|low<<auxShift, w}
__global__ __launch_bounds__(256) void k_binB8(const int* __restrict__ key,
        const int* __restrict__ aux, const float* __restrict__ wv, int nE,
        int shift, int auxShift, int* __restrict__ gcur, int2* __restrict__ tmp) {
    __shared__ int2 stage[B8_CHUNK];
    __shared__ int dest[B8_CHUNK];
    __shared__ int cnt[256], boff[256], gbase[256], curl[256];
    __shared__ int sc[256];
    int t = threadIdx.x;
    int base = blockIdx.x * B8_CHUNK;
    int nloc = nE - base; if (nloc > B8_CHUNK) nloc = B8_CHUNK;
    cnt[t] = 0;
    __syncthreads();
    for (int i = t; i < nloc; i += 256)
        atomicAdd(&cnt[key[base + i] >> shift], 1);
    __syncthreads();
    int v = cnt[t];
    sc[t] = v;
    __syncthreads();
    for (int o = 1; o < 256; o <<= 1) {
        int u = (t >= o) ? sc[t - o] : 0;
        __syncthreads();
        sc[t] += u;
        __syncthreads();
    }
    boff[t] = sc[t] - v;
    curl[t] = sc[t] - v;
    gbase[t] = atomicAdd(&gcur[t], v);
    __syncthreads();
    int lowmask = (1 << shift) - 1;
    for (int i = t; i < nloc; i += 256) {
        int e = base + i;
        int k = key[e];
        int b = k >> shift;
        int2 pay;
        pay.x = aux[e] | ((k & lowmask) << auxShift);
        pay.y = __float_as_int(wv[e]);
        int pos = atomicAdd(&curl[b], 1);
        stage[pos] = pay;
        dest[pos] = gbase[b] + (pos - boff[b]);
    }
    __syncthreads();
    for (int s = t; s < nloc; s += 256) tmp[dest[s]] = stage[s];
}

// ---- pass C: within-bucket counting sort into final CSR (LDS staged)
__global__ __launch_bounds__(256) void k_binC_kg(const unsigned* __restrict__ tmp,
        const int* __restrict__ off, unsigned* __restrict__ dst) {
    __shared__ unsigned stage[KG_CAP];
    __shared__ int curl[512];
    int b = blockIdx.x;
    int nbase = b << 9;
    int nlim = NE - nbase; if (nlim > 512) nlim = 512;
    if (nlim <= 0) return;
    int t = threadIdx.x;
    int r0 = off[nbase];
    int r1 = off[nbase + nlim];
    int cntb = r1 - r0;
    for (int i = t; i < nlim; i += 256) curl[i] = off[nbase + i] - r0;
    __syncthreads();
    if (cntb <= KG_CAP) {
        for (int s = t; s < cntb; s += 256) {
            unsigned pay = tmp[r0 + s];
            int l = (pay >> 21) & 511;
            int pos = atomicAdd(&curl[l], 1);
            stage[pos] = pay;
        }
        __syncthreads();
        for (int s = t; s < cntb; s += 256) dst[r0 + s] = stage[s];
    } else {
        for (int s = t; s < cntb; s += 256) {
            unsigned pay = tmp[r0 + s];
            int l = (pay >> 21) & 511;
            int pos = atomicAdd(&curl[l], 1);
            dst[r0 + pos] = pay;
        }
    }
}

__global__ __launch_bounds__(256) void k_binC8(const int2* __restrict__ tmp,
        const int* __restrict__ off, int2* __restrict__ dst, int nnodes,
        int shift, int auxShift) {
    __shared__ int2 stage[C8_CAP];
    __shared__ int curl[512];
    int b = blockIdx.x;
    int nbase = b << shift;
    int nlim = nnodes - nbase; if (nlim > (1 << shift)) nlim = 1 << shift;
    if (nlim <= 0) return;
    int t = threadIdx.x;
    int r0 = off[nbase];
    int r1 = off[nbase + nlim];
    int cntb = r1 - r0;
    int lowmask = (1 << shift) - 1;
    for (int i = t; i < nlim; i += 256) curl[i] = off[nbase + i] - r0;
    __syncthreads();
    if (cntb <= C8_CAP) {
        for (int s = t; s < cntb; s += 256) {
            int2 pay = tmp[r0 + s];
            int l = (pay.x >> auxShift) & lowmask;
            int pos = atomicAdd(&curl[l], 1);
            stage[pos] = pay;
        }
        __syncthreads();
        for (int s = t; s < cntb; s += 256) dst[r0 + s] = stage[s];
    } else {
        for (int s = t; s < cntb; s += 256) {
            int2 pay = tmp[r0 + s];
            int l = (pay.x >> auxShift) & lowmask;
            int pos = atomicAdd(&curl[l], 1);
            dst[r0 + pos] = pay;
        }
    }
}

#define SHFL_RED(p) \
    p += __shfl_xor(p, 16, 64); p += __shfl_xor(p, 8, 64); \
    p += __shfl_xor(p, 4, 64);  p += __shfl_xor(p, 2, 64); \
    p += __shfl_xor(p, 1, 64);

// fused per-node entity aggregation (fp16 gathers, f32 math)
__global__ __launch_bounds__(256) void k_ent(const __half* __restrict__ qmH,
        const float* __restrict__ relf, const __half* __restrict__ entH,
        const __half* __restrict__ usrH,
        const int* __restrict__ kg_off, const unsigned* __restrict__ kg_tr,
        const int* __restrict__ iu_off, const int2* __restrict__ iu_iw,
        float* __restrict__ eacc, __half* __restrict__ entHout) {
    int w = __builtin_amdgcn_readfirstlane(threadIdx.x >> 6);
    int node = blockIdx.x * 4 + w;
    if (node >= NE) return;
    int d = threadIdx.x & 63;
    const float SC = 0.17677669529663687f; // 1/sqrt(32)
    float qh = __half2float(qmH[(long)node * 64 + d]);
    int b0 = kg_off[node], b1 = kg_off[node + 1];
    int deg = b1 - b0;

    float m = -INFINITY, ssum = 0.f, acc = 0.f;
    int s = b0;
    for (; s + 4 <= b1; s += 4) {
        float sc[4], val[4];
#pragma unroll
        for (int j = 0; j < 4; j++) {
            unsigned tr = kg_tr[s + j];
            int tl = tr & 0x1FFFF, rr = (tr >> 17) & 15;
            float rl = relf[rr * 64 + d];
            float qt = __half2float(qmH[(long)tl * 64 + d]);
            val[j] = __half2float(entH[(long)tl * 64 + d]) * rl;
            float p = qh * qt * rl;
            SHFL_RED(p)
            sc[j] = p * SC;
        }
        float cmax = fmaxf(fmaxf(sc[0], sc[1]), fmaxf(sc[2], sc[3]));
        float mn = fmaxf(m, cmax);
        float scale = __expf(m - mn);
        ssum *= scale; acc *= scale;
#pragma unroll
        for (int j = 0; j < 4; j++) {
            float e = __expf(sc[j] - mn);
            ssum += e;
            acc += val[j] * e;
        }
        m = mn;
    }
    for (; s < b1; s++) {
        unsigned tr = kg_tr[s];
        int tl = tr & 0x1FFFF, rr = (tr >> 17) & 15;
        float rl = relf[rr * 64 + d];
        float qt = __half2float(qmH[(long)tl * 64 + d]);
        float v = __half2float(entH[(long)tl * 64 + d]) * rl;
        float p = qh * qt * rl;
        SHFL_RED(p)
        float scv = p * SC;
        float mn = fmaxf(m, scv);
        float scale = __expf(m - mn);
        float e = __expf(scv - mn);
        ssum = ssum * scale + e;
        acc = acc * scale + v * e;
        m = mn;
    }
    if (deg > 0) acc /= ssum;

    float ss = acc * acc;
    SHFL_RED(ss)
    ss += __shfl_xor(ss, 32, 64);
    float scale = 1.f / fmaxf(sqrtf(ss), 1e-12f);
    acc *= scale;

    int c0 = iu_off[node], c1 = iu_off[node + 1];
    int t = c0;
    for (; t + 4 <= c1; t += 4) {
        int2 p0 = iu_iw[t + 0], p1 = iu_iw[t + 1], p2 = iu_iw[t + 2], p3 = iu_iw[t + 3];
        float a0 = __int_as_float(p0.y) * __half2float(usrH[(long)(p0.x & 0xFFFF) * 64 + d]);
        float a1 = __int_as_float(p1.y) * __half2float(usrH[(long)(p1.x & 0xFFFF) * 64 + d]);
        float a2 = __int_as_float(p2.y) * __half2float(usrH[(long)(p2.x & 0xFFFF) * 64 + d]);
        float a3 = __int_as_float(p3.y) * __half2float(usrH[(long)(p3.x & 0xFFFF) * 64 + d]);
        acc += (a0 + a1) + (a2 + a3);
    }
    for (; t < c1; t++) {
        int2 pw = iu_iw[t];
        acc += __int_as_float(pw.y) * __half2float(usrH[(long)(pw.x & 0xFFFF) * 64 + d]);
    }
    long idx = (long)node * 64 + d;
    eacc[idx] += acc;
    entHout[idx] = __float2half(acc);
}

// user <- item gather (fp16 rows)
__global__ __launch_bounds__(256) void k_usr(const __half* __restrict__ entH,
        const int* __restrict__ ui_off, const int2* __restrict__ ui_iw,
        float* __restrict__ uacc, __half* __restrict__ usrHout) {
    int w = __builtin_amdgcn_readfirstlane(threadIdx.x >> 6);
    int node = blockIdx.x * 4 + w;
    if (node >= NU) return;
    int d = threadIdx.x & 63;
    int b0 = ui_off[node], b1 = ui_off[node + 1];
    float acc = 0.f;
    int s = b0;
    for (; s + 4 <= b1; s += 4) {
        int2 p0 = ui_iw[s + 0], p1 = ui_iw[s + 1], p2 = ui_iw[s + 2], p3 = ui_iw[s + 3];
        float a0 = __int_as_float(p0.y) * __half2float(entH[(long)(p0.x & 0x1FFFF) * 64 + d]);
        float a1 = __int_as_float(p1.y) * __half2float(entH[(long)(p1.x & 0x1FFFF) * 64 + d]);
        float a2 = __int_as_float(p2.y) * __half2float(entH[(long)(p2.x & 0x1FFFF) * 64 + d]);
        float a3 = __int_as_float(p3.y) * __half2float(entH[(long)(p3.x & 0x1FFFF) * 64 + d]);
        acc += (a0 + a1) + (a2 + a3);
    }
    for (; s < b1; s++) {
        int2 pw = ui_iw[s];
        acc += __int_as_float(pw.y) * __half2float(entH[(long)(pw.x & 0x1FFFF) * 64 + d]);
    }
    long idx = (long)node * 64 + d;
    uacc[idx] += acc;
    usrHout[idx] = __float2half(acc);
}

// out = concat((usr0 + uacc)/3, (ent0 + eacc)/3)
__global__ void k_final(const float* __restrict__ usr0, const float* __restrict__ uacc,
                        const float* __restrict__ ent0, const float* __restrict__ eacc,
                        float* __restrict__ out) {
    int i = blockIdx.x * blockDim.x + threadIdx.x;
    const float inv3 = 1.f / 3.f;
    if (i < NU * DIM) {
        out[i] = (usr0[i] + uacc[i]) * inv3;
    } else if (i < (NU + NE) * DIM) {
        int j = i - NU * DIM;
        out[i] = (ent0[j] + eacc[j]) * inv3;
    }
}

extern "C" void kernel_launch(void* const* d_in, const int* in_sizes, int n_in,
                              void* d_out, int out_size, void* d_ws, size_t ws_size,
                              hipStream_t stream) {
    const float* usr0  = (const float*)d_in[1];
    const float* ent0  = (const float*)d_in[2];
    const int*   inter = (const int*)d_in[3];
    const float* iwf   = (const float*)d_in[4];
    const int*   eidx  = (const int*)d_in[5];
    const int*   etype = (const int*)d_in[6];
    const float* relf  = (const float*)d_in[7];
    const float* wqf   = (const float*)d_in[8];
    float* out = (float*)d_out;

    const int* eh = eidx;
    const int* et = eidx + EKG;
    const int* iu = inter;
    const int* ii = inter + EIN;

    // ---- workspace layout (4B words), ~136 MB ----
    float* p = (float*)d_ws;
    float* eacc = p;  p += (long)NE * DIM;        // contiguous accs -> one memset
    float* uacc = p;  p += (long)NU * DIM;
    __half* qmH   = (__half*)p;  p += (long)NE * DIM / 2;
    __half* entHa = (__half*)p;  p += (long)NE * DIM / 2;
    __half* entHb = (__half*)p;  p += (long)NE * DIM / 2;
    __half* usrHa = (__half*)p;  p += (long)NU * DIM / 2;
    __half* usrHb = (__half*)p;  p += (long)NU * DIM / 2;
    int* kg_cnt = (int*)p;      p += NE;
    int* ui_cnt = (int*)p;      p += NU;
    int* iu_cnt = (int*)p;      p += NE;
    int* kg_off = (int*)p;      p += NE + 2;
    int* ui_off = (int*)p;      p += NU + 2;
    int* iu_off = (int*)p;      p += NE + 2;
    int* kg_g   = (int*)p;      p += 256;
    int* ui_g   = (int*)p;      p += 256;
    int* iu_g   = (int*)p;      p += 256;
    unsigned* kg_tr  = (unsigned*)p; p += EKG;
    unsigned* kg_tmp = (unsigned*)p; p += EKG;
    int2* ui_iw  = (int2*)p;    p += (long)EIN * 2;
    int2* ui_tmp = (int2*)p;    p += (long)EIN * 2;
    int2* iu_iw  = (int2*)p;    p += (long)EIN * 2;
    int2* iu_tmp = (int2*)p;    p += (long)EIN * 2;
    int* pk = (int*)p;          p += 128;
    int* pu = (int*)p;          p += 128;
    int* pi = (int*)p;          p += 128;

    const int B = 256;
    const int NBK = (NE + 1023) / 1024;   // 98
    const int NBU = (NU + 1023) / 1024;   // 49

    // ---- init: zero accumulators + cnts; layer-0 fp16 mirrors ----
    hipMemsetAsync(eacc, 0, (size_t)(NE + NU) * DIM * 4, stream);
    hipMemsetAsync(kg_cnt, 0, (size_t)(NE + NU + NE) * 4, stream);
    k_castH<<<(NE * DIM + B - 1) / B, B, 0, stream>>>(ent0, usr0, entHa, usrHa);

    // ---- CSR build ----
    int gEdge = (EKG + B - 1) / B;
    k_hist<<<gEdge, B, 0, stream>>>(eh, iu, ii, kg_cnt, ui_cnt, iu_cnt);
    k_scan_p1<<<NBK, 256, 0, stream>>>(kg_cnt, NE, pk);
    k_scan_p1<<<NBU, 256, 0, stream>>>(ui_cnt, NU, pu);
    k_scan_p1<<<NBK, 256, 0, stream>>>(iu_cnt, NE, pi);
    k_scan_p2<<<3, 64, 0, stream>>>(pk, NBK, kg_off + NE,
                                    pu, NBU, ui_off + NU,
                                    pi, NBK, iu_off + NE);
    k_scan_p3<<<NBK, 256, 0, stream>>>(kg_cnt, NE, pk, kg_off);
    k_scan_p3<<<NBU, 256, 0, stream>>>(ui_cnt, NU, pu, ui_off);
    k_scan_p3<<<NBK, 256, 0, stream>>>(iu_cnt, NE, pi, iu_off);
    k_initgcur<<<1, 256, 0, stream>>>(kg_off, ui_off, iu_off, kg_g, ui_g, iu_g);
    k_binB_kg<<<(EKG + KG_CHUNK - 1) / KG_CHUNK, 256, 0, stream>>>(eh, et, etype, kg_g, kg_tmp);
    k_binB8<<<(EIN + B8_CHUNK - 1) / B8_CHUNK, 256, 0, stream>>>(iu, ii, iwf, EIN, 8, 17, ui_g, ui_tmp);
    k_binB8<<<(EIN + B8_CHUNK - 1) / B8_CHUNK, 256, 0, stream>>>(ii, iu, iwf, EIN, 9, 16, iu_g, iu_tmp);
    k_binC_kg<<<KG_NBUCK, 256, 0, stream>>>(kg_tmp, kg_off, kg_tr);
    k_binC8<<<(NU + 255) >> 8, 256, 0, stream>>>(ui_tmp, ui_off, ui_iw, NU, 8, 17);
    k_binC8<<<(NE + 511) >> 9, 256, 0, stream>>>(iu_tmp, iu_off, iu_iw, NE, 9, 16);

    // ---- layer 0 ----
    k_gemm_f<<<NE / 4, 256, 0, stream>>>(ent0, wqf, qmH, NE);
    k_ent<<<(NE + 3) / 4, 256, 0, stream>>>(qmH, relf, entHa, usrHa,
                                            kg_off, kg_tr, iu_off, iu_iw, eacc, entHb);
    k_usr<<<(NU + 3) / 4, 256, 0, stream>>>(entHa, ui_off, ui_iw, uacc, usrHb);
    // ---- layer 1 ----
    k_gemm_h<<<NE / 4, 256, 0, stream>>>(entHb, wqf, qmH, NE);
    k_ent<<<(NE + 3) / 4, 256, 0, stream>>>(qmH, relf, entHb, usrHb,
                                            kg_off, kg_tr, iu_off, iu_iw, eacc, entHa);
    k_usr<<<(NU + 3) / 4, 256, 0, stream>>>(entHb, ui_off, ui_iw, uacc, usrHa);

    k_final<<<((NU + NE) * DIM + B - 1) / B, B, 0, stream>>>(usr0, uacc, ent0, eacc, out);
}